// Round 1
// baseline (2330.712 us; speedup 1.0000x reference)
//
#include <hip/hip_runtime.h>
#include <hip/hip_bf16.h>
#include <math.h>

// ---------------- problem constants ----------------
#define B_      8
#define NT_     16
#define DIM_    768
#define HEADS_  8
#define HD_     96
#define PIX_    1024
#define NTOK_   1040              // NT + PIX
#define QSTR_   6389760ull        // B*HEADS*NTOK*HD

// ---------------- workspace layout (float offsets) ----------------
// total floats: 27,852,864 + 1024 (partials) -> ~111.4 MB. ws must be >= that.
#define OFF_XC       0ull          // 6,389,760   (B,NTOK,DIM)  reused as attn_cat
#define OFF_Q        6389760ull    // 3 * 6,389,760  q,k,v (B,H,NTOK,HD)
#define OFF_TPOUT    25559040ull   // 98,304      (B,NT,DIM)
#define OFF_CHANP    25657344ull   // 131,072     (B,NT,PIX)
#define OFF_RAWCHAN  25788416ull   // 1,572,864   (B,16,NT,DIM)
#define OFF_CHP      27361280ull   // 98,304      (B,NT,DIM)
#define OFF_FE2      27459584ull   // 393,216     (B,NT,4,DIM)
#define OFF_STATS    27852800ull   // 1024        per-(b,t) partial sums [128][4][2]

// ---------------- output layout (float offsets) ----------------
#define OUT_XOUT   0ull            // (B,PIX,DIM)          6,291,456
#define OUT_RAW    6291456ull      // (B,H,NTOK,NTOK)     69,222,400
#define OUT_ATTN   75513856ull     // (B,H,NTOK,NTOK)     69,222,400
#define OUT_RAWCH  144736256ull    // (B,NT,DIM,4,4)       1,572,864
#define OUT_ATTNCH 146309120ull    // (B,NT,DIM,4,4)       1,572,864
#define OUT_QOUT   147881984ull    // (B,NT,DIM)              98,304

// =================== xc = concat(task_prompts, x) ===================
__global__ __launch_bounds__(256) void build_xc(const float* __restrict__ tp,
                                                const float* __restrict__ x,
                                                float* __restrict__ xc) {
    size_t idx = (size_t)blockIdx.x * 256 + threadIdx.x;  // < B*NTOK*DIM
    int c = idx % DIM_;
    int n = (idx / DIM_) % NTOK_;
    int b = idx / ((size_t)DIM_ * NTOK_);
    float v;
    if (n < NT_) v = tp[((size_t)b * NT_ + n) * DIM_ + c];
    else         v = x[((size_t)b * PIX_ + (n - NT_)) * DIM_ + c];
    xc[idx] = v;
}

// =================== generic tiled SGEMM: C = A(MxK) @ Bw(NnxK)^T + bias ===================
// mode 0: C0[m*Nn+n]
// mode 1: qkv scatter into q/k/v (B,H,NTOK,HD), C0 = q base (k,v at +QSTR_,+2*QSTR_)
// mode 2: proj split: rows n<NT -> C1 (tp_out), else C0 (x_out)
__global__ __launch_bounds__(256) void sgemm_nt(const float* __restrict__ A,
                                                const float* __restrict__ Bw,
                                                const float* __restrict__ bias,
                                                float* __restrict__ C0,
                                                float* __restrict__ C1,
                                                int M, int Nn, int K, int mode) {
    __shared__ float As[16][65];
    __shared__ float Bs[16][65];
    int bm = blockIdx.x, bn = blockIdx.y;
    int tid = threadIdx.x;
    int tx = tid % 16, ty = tid / 16;
    int arow = bm * 64, bcol = bn * 64;
    float acc[4][4] = {};
    for (int kt = 0; kt < K; kt += 16) {
        for (int l = tid; l < 64 * 16; l += 256) {
            int r = l / 16, c = l % 16;
            As[c][r] = A[(size_t)(arow + r) * K + kt + c];
            Bs[c][r] = Bw[(size_t)(bcol + r) * K + kt + c];
        }
        __syncthreads();
#pragma unroll
        for (int kk = 0; kk < 16; ++kk) {
            float a[4], b[4];
#pragma unroll
            for (int i = 0; i < 4; ++i) a[i] = As[kk][i * 16 + ty];
#pragma unroll
            for (int j = 0; j < 4; ++j) b[j] = Bs[kk][j * 16 + tx];
#pragma unroll
            for (int i = 0; i < 4; ++i)
#pragma unroll
                for (int j = 0; j < 4; ++j) acc[i][j] += a[i] * b[j];
        }
        __syncthreads();
    }
#pragma unroll
    for (int i = 0; i < 4; ++i) {
#pragma unroll
        for (int j = 0; j < 4; ++j) {
            int m = arow + i * 16 + ty;
            int n = bcol + j * 16 + tx;
            float v = acc[i][j] + (bias ? bias[n] : 0.f);
            if (mode == 0) {
                C0[(size_t)m * Nn + n] = v;
            } else if (mode == 1) {
                int b = m / NTOK_, nn = m % NTOK_;
                int s = n / DIM_, rem = n % DIM_;
                int h = rem / HD_, d = rem % HD_;
                C0[(size_t)s * QSTR_ + (((size_t)b * HEADS_ + h) * NTOK_ + nn) * HD_ + d] = v;
            } else {
                int b = m / NTOK_, nn = m % NTOK_;
                if (nn < NT_) C1[((size_t)b * NT_ + nn) * DIM_ + n] = v;
                else          C0[((size_t)b * PIX_ + (nn - NT_)) * DIM_ + n] = v;
            }
        }
    }
}

// =================== raw_spa = Q @ K^T (unscaled) ===================
__global__ __launch_bounds__(256) void spa_scores(const float* __restrict__ q,
                                                  const float* __restrict__ k,
                                                  float* __restrict__ raw) {
    __shared__ float Qs[64][100];
    __shared__ float Ks[64][100];
    int bi = blockIdx.x, bj = blockIdx.y, bh = blockIdx.z;
    int tid = threadIdx.x;
    const float* qb = q + (size_t)bh * NTOK_ * HD_;
    const float* kb = k + (size_t)bh * NTOK_ * HD_;
    int i0 = bi * 64, j0 = bj * 64;
    for (int l = tid; l < 64 * 96; l += 256) {
        int r = l / 96, c = l % 96;
        Qs[r][c] = (i0 + r < NTOK_) ? qb[(size_t)(i0 + r) * HD_ + c] : 0.f;
        Ks[r][c] = (j0 + r < NTOK_) ? kb[(size_t)(j0 + r) * HD_ + c] : 0.f;
    }
    __syncthreads();
    int tx = tid % 16, ty = tid / 16;
    float acc[4][4] = {};
#pragma unroll 8
    for (int kk = 0; kk < 96; ++kk) {
        float a[4], b[4];
#pragma unroll
        for (int i = 0; i < 4; ++i) a[i] = Qs[i * 16 + ty][kk];
#pragma unroll
        for (int j = 0; j < 4; ++j) b[j] = Ks[j * 16 + tx][kk];
#pragma unroll
        for (int i = 0; i < 4; ++i)
#pragma unroll
            for (int j = 0; j < 4; ++j) acc[i][j] += a[i] * b[j];
    }
#pragma unroll
    for (int i = 0; i < 4; ++i)
#pragma unroll
        for (int j = 0; j < 4; ++j) {
            int gi = i0 + i * 16 + ty, gj = j0 + j * 16 + tx;
            if (gi < NTOK_ && gj < NTOK_)
                raw[((size_t)bh * NTOK_ + gi) * NTOK_ + gj] = acc[i][j];
        }
}

// =================== spa softmax (row length 1040) ===================
__global__ __launch_bounds__(256) void spa_softmax(const float* __restrict__ raw,
                                                   float* __restrict__ attn) {
    size_t row = blockIdx.x;
    const float* rp = raw + row * NTOK_;
    float* ap = attn + row * NTOK_;
    int tid = threadIdx.x;
    const float scale = 0.1020620726159658f;  // 96^-0.5
    float vals[5];
    float m = -INFINITY;
#pragma unroll
    for (int i = 0; i < 5; ++i) {
        int idx = tid + i * 256;
        vals[i] = (idx < NTOK_) ? rp[idx] * scale : -INFINITY;
        m = fmaxf(m, vals[i]);
    }
    __shared__ float redm[4], reds[4];
    for (int off = 32; off; off >>= 1) m = fmaxf(m, __shfl_xor(m, off));
    if ((tid & 63) == 0) redm[tid >> 6] = m;
    __syncthreads();
    m = fmaxf(fmaxf(redm[0], redm[1]), fmaxf(redm[2], redm[3]));
    float s = 0.f;
#pragma unroll
    for (int i = 0; i < 5; ++i) {
        int idx = tid + i * 256;
        if (idx < NTOK_) { vals[i] = __expf(vals[i] - m); s += vals[i]; }
    }
    for (int off = 32; off; off >>= 1) s += __shfl_xor(s, off);
    if ((tid & 63) == 0) reds[tid >> 6] = s;
    __syncthreads();
    s = reds[0] + reds[1] + reds[2] + reds[3];
    float inv = 1.f / s;
#pragma unroll
    for (int i = 0; i < 5; ++i) {
        int idx = tid + i * 256;
        if (idx < NTOK_) ap[idx] = vals[i] * inv;
    }
}

// =================== attn_cat = P @ V, written as (B,NTOK,DIM) ===================
__global__ __launch_bounds__(256) void spa_pv(const float* __restrict__ attn,
                                              const float* __restrict__ v,
                                              float* __restrict__ attn_cat) {
    __shared__ float Ps[32][33];
    __shared__ float Vs[32][100];
    int bi = blockIdx.x;   // 33 i-tiles of 32
    int bh = blockIdx.y;   // 64
    int b = bh / HEADS_, h = bh % HEADS_;
    int tid = threadIdx.x;
    int r = tid % 32, g = tid / 32;
    int d0 = g * 12;
    float acc[12] = {};
    int i0 = bi * 32;
    const float* ap = attn + (size_t)bh * NTOK_ * NTOK_;
    const float* vp = v + (size_t)bh * NTOK_ * HD_;
    for (int jc = 0; jc < NTOK_; jc += 32) {
        for (int l = tid; l < 32 * 32; l += 256) {
            int rr = l / 32, jj = l % 32;
            Ps[rr][jj] = (i0 + rr < NTOK_ && jc + jj < NTOK_)
                             ? ap[(size_t)(i0 + rr) * NTOK_ + jc + jj] : 0.f;
        }
        for (int l = tid; l < 32 * 96; l += 256) {
            int rr = l / 96, c = l % 96;
            Vs[rr][c] = (jc + rr < NTOK_) ? vp[(size_t)(jc + rr) * HD_ + c] : 0.f;
        }
        __syncthreads();
#pragma unroll
        for (int jj = 0; jj < 32; ++jj) {
            float p = Ps[r][jj];
#pragma unroll
            for (int i = 0; i < 12; ++i) acc[i] += p * Vs[jj][d0 + i];
        }
        __syncthreads();
    }
    int gi = i0 + r;
    if (gi < NTOK_) {
        float* op = attn_cat + ((size_t)b * NTOK_ + gi) * DIM_ + h * HD_ + d0;
#pragma unroll
        for (int i = 0; i < 12; ++i) op[i] = acc[i];
    }
}

// =================== windowed channel scores ===================
// raw_chan[b,w,t,c] = sum_d chan_prompts[b,t,pix(w,d)] * x[b,pix(w,d),c]
__global__ __launch_bounds__(256) void chan_scores(const float* __restrict__ chanp,
                                                   const float* __restrict__ x,
                                                   float* __restrict__ rawchan_ws,
                                                   float* __restrict__ out_raw) {
    int blk = blockIdx.x;  // b*16 + w
    int b = blk / 16, w = blk % 16;
    int nh = w / 4, nw = w % 4;
    __shared__ float qp[16][65];
    __shared__ float xs[64][17];
    int tid = threadIdx.x;
    for (int l = tid; l < 16 * 64; l += 256) {
        int t = l / 64, d = l % 64;
        int wh = d / 8, ww = d % 8;
        int pix = (nh * 8 + wh) * 32 + nw * 8 + ww;
        qp[t][d] = chanp[((size_t)b * NT_ + t) * PIX_ + pix];
    }
    __syncthreads();
    int t = tid % 16, cl = tid / 16;
    for (int cc = 0; cc < 48; ++cc) {
        for (int l = tid; l < 64 * 16; l += 256) {
            int d = l / 16, c2 = l % 16;
            int wh = d / 8, ww = d % 8;
            int pix = (nh * 8 + wh) * 32 + nw * 8 + ww;
            xs[d][c2] = x[((size_t)b * PIX_ + pix) * DIM_ + cc * 16 + c2];
        }
        __syncthreads();
        float acc = 0.f;
#pragma unroll
        for (int d = 0; d < 64; ++d) acc += qp[t][d] * xs[d][cl];
        int c = cc * 16 + cl;
        rawchan_ws[(((size_t)b * 16 + w) * NT_ + t) * DIM_ + c] = acc;
        out_raw[(((size_t)b * NT_ + t) * DIM_ + c) * 16 + w] = acc;
        __syncthreads();
    }
}

// =================== chan softmax over c (768), scattered write ===================
__global__ __launch_bounds__(256) void chan_softmax(const float* __restrict__ rawchan_ws,
                                                    float* __restrict__ out_attn) {
    int row = blockIdx.x;  // (b*16+w)*16 + t, 2048 rows
    int b = row / 256;
    int w = (row / 16) % 16;
    int t = row % 16;
    const float* rp = rawchan_ws + (size_t)row * DIM_;
    int tid = threadIdx.x;
    float vals[3];
    float m = -INFINITY;
#pragma unroll
    for (int i = 0; i < 3; ++i) {
        vals[i] = rp[tid + i * 256] * 0.125f;  // 64^-0.5
        m = fmaxf(m, vals[i]);
    }
    __shared__ float redm[4], reds[4];
    for (int off = 32; off; off >>= 1) m = fmaxf(m, __shfl_xor(m, off));
    if ((tid & 63) == 0) redm[tid >> 6] = m;
    __syncthreads();
    m = fmaxf(fmaxf(redm[0], redm[1]), fmaxf(redm[2], redm[3]));
    float s = 0.f;
#pragma unroll
    for (int i = 0; i < 3; ++i) { vals[i] = __expf(vals[i] - m); s += vals[i]; }
    for (int off = 32; off; off >>= 1) s += __shfl_xor(s, off);
    if ((tid & 63) == 0) reds[tid >> 6] = s;
    __syncthreads();
    s = reds[0] + reds[1] + reds[2] + reds[3];
    float inv = 1.f / s;
#pragma unroll
    for (int i = 0; i < 3; ++i) {
        int c = tid + i * 256;
        out_attn[(((size_t)b * NT_ + t) * DIM_ + c) * 16 + w] = vals[i] * inv;
    }
}

// =================== quaternion double conv (per (b,t) block) ===================
__global__ __launch_bounds__(256) void quat_conv(const float* __restrict__ tp,
                                                 const float* __restrict__ tpo,
                                                 const float* __restrict__ chp,
                                                 const float* __restrict__ qf_r, const float* __restrict__ qf_i,
                                                 const float* __restrict__ qf_j, const float* __restrict__ qf_k,
                                                 const float* __restrict__ qf_b,
                                                 const float* __restrict__ dqf_r, const float* __restrict__ dqf_i,
                                                 const float* __restrict__ dqf_j, const float* __restrict__ dqf_k,
                                                 const float* __restrict__ dqf_b,
                                                 float* __restrict__ fe2_out,
                                                 float* __restrict__ partials) {
    int blk = blockIdx.x;  // b*16 + t
    int b = blk / NT_, t = blk % NT_;
    __shared__ float w1[8][4][3];
    __shared__ float w2[8][4][3];
    __shared__ float w2c[4][8][3];
    __shared__ float qs[4][770];
    __shared__ float fs[8][770];
    __shared__ float wsum[4][4], wsq[4][4];
    int tid = threadIdx.x;
    if (tid < 96) {
        int o = tid / 12, rest = tid % 12, ic = rest / 3, tap = rest % 3;
        int g = o / 2, oo = o % 2;
        const int   cidx[4][4] = {{0, 1, 2, 3}, {1, 0, 3, 2}, {2, 3, 0, 1}, {3, 2, 1, 0}};
        const float csgn[4][4] = {{1, -1, -1, -1}, {1, 1, -1, 1}, {1, 1, 1, -1}, {1, -1, 1, 1}};
        const float* s1[4] = {qf_r, qf_i, qf_j, qf_k};
        const float* s2[4] = {dqf_r, dqf_i, dqf_j, dqf_k};
        w1[o][ic][tap] = csgn[g][ic] * s1[cidx[g][ic]][oo * 3 + tap];
        w2[o][ic][tap] = csgn[g][ic] * s2[cidx[g][ic]][oo * 3 + tap];
    }
    for (int l = tid; l < DIM_; l += 256) {
        size_t base = ((size_t)b * NT_ + t) * DIM_ + l;
        qs[0][1 + l] = 0.f;
        qs[1][1 + l] = tp[base];
        qs[2][1 + l] = tpo[base];
        qs[3][1 + l] = chp[base];
    }
    if (tid < 4) { qs[tid][0] = 0.f; qs[tid][769] = 0.f; }
    if (tid < 8) { fs[tid][0] = 0.f; fs[tid][769] = 0.f; }
    __syncthreads();
    if (tid < 96) {  // w2c[o2][i2][tap] = w2[i2][o2][2-tap]
        int o2 = tid / 24, rest = tid % 24, i2 = rest / 3, tap = rest % 3;
        w2c[o2][i2][tap] = w2[i2][o2][2 - tap];
    }
    for (int l = tid; l < DIM_; l += 256) {
#pragma unroll
        for (int o = 0; o < 8; ++o) {
            float a = qf_b[o];
#pragma unroll
            for (int ic = 0; ic < 4; ++ic)
#pragma unroll
                for (int tap = 0; tap < 3; ++tap) a += w1[o][ic][tap] * qs[ic][l + tap];
            fs[o][1 + l] = a;
        }
    }
    __syncthreads();
    float lsum[4] = {}, lsq[4] = {};
    for (int l = tid; l < DIM_; l += 256) {
#pragma unroll
        for (int o2 = 0; o2 < 4; ++o2) {
            float a = dqf_b[o2];
#pragma unroll
            for (int i2 = 0; i2 < 8; ++i2)
#pragma unroll
                for (int tap = 0; tap < 3; ++tap) a += w2c[o2][i2][tap] * fs[i2][l + tap];
            fe2_out[((size_t)blk * 4 + o2) * DIM_ + l] = a;
            lsum[o2] += a;
            lsq[o2] += a * a;
        }
    }
    int wid = tid >> 6;
#pragma unroll
    for (int o2 = 0; o2 < 4; ++o2) {
        float s = lsum[o2], q = lsq[o2];
        for (int off = 32; off; off >>= 1) { s += __shfl_xor(s, off); q += __shfl_xor(q, off); }
        if ((tid & 63) == 0) { wsum[wid][o2] = s; wsq[wid][o2] = q; }
    }
    __syncthreads();
    if (tid < 4) {
        float s = wsum[0][tid] + wsum[1][tid] + wsum[2][tid] + wsum[3][tid];
        float q = wsq[0][tid] + wsq[1][tid] + wsq[2][tid] + wsq[3][tid];
        partials[(size_t)blk * 8 + tid * 2 + 0] = s;
        partials[(size_t)blk * 8 + tid * 2 + 1] = q;
    }
}

// =================== BN (per b,ch over t,c) + exact GELU + channel mix ===================
__global__ __launch_bounds__(256) void bn_gelu_out(const float* __restrict__ fe2,
                                                   const float* __restrict__ partials,
                                                   const float* __restrict__ bn_g,
                                                   const float* __restrict__ bn_b,
                                                   const float* __restrict__ qfto,
                                                   float* __restrict__ out5) {
    int blk = blockIdx.x;  // b*16 + t
    int b = blk / NT_;
    int tid = threadIdx.x;
    float mean[4], rstd[4], gam[4], bet[4], qw[4];
#pragma unroll
    for (int kk = 0; kk < 4; ++kk) {
        float s = 0.f, q = 0.f;
        for (int t2 = 0; t2 < 16; ++t2) {
            const float* p = partials + ((size_t)(b * NT_ + t2) * 8 + kk * 2);
            s += p[0];
            q += p[1];
        }
        float mu = s * (1.f / 12288.f);
        float var = q * (1.f / 12288.f) - mu * mu;
        mean[kk] = mu;
        rstd[kk] = rsqrtf(var + 1e-5f);
        gam[kk] = bn_g[kk];
        bet[kk] = bn_b[kk];
        qw[kk] = qfto[kk];
    }
    for (int l = tid; l < DIM_; l += 256) {
        float acc = 0.f;
#pragma unroll
        for (int kk = 0; kk < 4; ++kk) {
            float v = fe2[((size_t)blk * 4 + kk) * DIM_ + l];
            float nrm = (v - mean[kk]) * rstd[kk] * gam[kk] + bet[kk];
            float ge = 0.5f * nrm * (1.f + erff(nrm * 0.7071067811865475f));
            acc += ge * qw[kk];
        }
        out5[(size_t)blk * DIM_ + l] = acc;
    }
}

// =================== launch ===================
extern "C" void kernel_launch(void* const* d_in, const int* in_sizes, int n_in,
                              void* d_out, int out_size, void* d_ws, size_t ws_size,
                              hipStream_t stream) {
    const float* x      = (const float*)d_in[0];
    const float* tp     = (const float*)d_in[1];
    const float* qkv_w  = (const float*)d_in[2];
    const float* proj_w = (const float*)d_in[3];
    const float* proj_b = (const float*)d_in[4];
    const float* tt_w   = (const float*)d_in[5];
    const float* tt_b   = (const float*)d_in[6];
    const float* tt1_w  = (const float*)d_in[7];
    const float* tt1_b  = (const float*)d_in[8];
    const float* qf_r   = (const float*)d_in[9];
    const float* qf_i   = (const float*)d_in[10];
    const float* qf_j   = (const float*)d_in[11];
    const float* qf_k   = (const float*)d_in[12];
    const float* qf_b   = (const float*)d_in[13];
    const float* dqf_r  = (const float*)d_in[14];
    const float* dqf_i  = (const float*)d_in[15];
    const float* dqf_j  = (const float*)d_in[16];
    const float* dqf_k  = (const float*)d_in[17];
    const float* dqf_b  = (const float*)d_in[18];
    const float* bn_g   = (const float*)d_in[19];
    const float* bn_b   = (const float*)d_in[20];
    const float* qfto   = (const float*)d_in[21];
    float* out = (float*)d_out;
    float* ws  = (float*)d_ws;

    // 1. xc = concat
    build_xc<<<24960, 256, 0, stream>>>(tp, x, ws + OFF_XC);
    // 2. qkv gemm -> q,k,v (B,H,N,HD)
    sgemm_nt<<<dim3(130, 36), 256, 0, stream>>>(ws + OFF_XC, qkv_w, nullptr,
                                                ws + OFF_Q, nullptr, 8320, 2304, 768, 1);
    // 3. raw scores (output 2)
    spa_scores<<<dim3(17, 17, 64), 256, 0, stream>>>(ws + OFF_Q, ws + OFF_Q + QSTR_, out + OUT_RAW);
    // 4. softmax (output 3)
    spa_softmax<<<66560, 256, 0, stream>>>(out + OUT_RAW, out + OUT_ATTN);
    // 5. PV -> attn_cat (reuse xc buffer)
    spa_pv<<<dim3(33, 64), 256, 0, stream>>>(out + OUT_ATTN, ws + OFF_Q + 2 * QSTR_, ws + OFF_XC);
    // 6. proj: x_out (output 1) + tp_out (ws)
    sgemm_nt<<<dim3(130, 12), 256, 0, stream>>>(ws + OFF_XC, proj_w, proj_b,
                                                out + OUT_XOUT, ws + OFF_TPOUT, 8320, 768, 768, 2);
    // 7. chan_prompts = tp @ tt_w^T + tt_b
    sgemm_nt<<<dim3(2, 16), 256, 0, stream>>>(tp, tt_w, tt_b,
                                              ws + OFF_CHANP, nullptr, 128, 1024, 768, 0);
    // 8. windowed channel scores (output 4 + ws)
    chan_scores<<<128, 256, 0, stream>>>(ws + OFF_CHANP, x, ws + OFF_RAWCHAN, out + OUT_RAWCH);
    // 9. chan softmax (output 5)
    chan_softmax<<<2048, 256, 0, stream>>>(ws + OFF_RAWCHAN, out + OUT_ATTNCH);
    // 10. ch_prompts = chan_prompts @ tt1_w^T + tt1_b
    sgemm_nt<<<dim3(2, 12), 256, 0, stream>>>(ws + OFF_CHANP, tt1_w, tt1_b,
                                              ws + OFF_CHP, nullptr, 128, 768, 1024, 0);
    // 11. quaternion double conv + BN partials
    quat_conv<<<128, 256, 0, stream>>>(tp, ws + OFF_TPOUT, ws + OFF_CHP,
                                       qf_r, qf_i, qf_j, qf_k, qf_b,
                                       dqf_r, dqf_i, dqf_j, dqf_k, dqf_b,
                                       ws + OFF_FE2, ws + OFF_STATS);
    // 12. BN + GELU + mix (output 6)
    bn_gelu_out<<<128, 256, 0, stream>>>(ws + OFF_FE2, ws + OFF_STATS, bn_g, bn_b, qfto,
                                         out + OUT_QOUT);
}

// Round 2
// 877.358 us; speedup vs baseline: 2.6565x; 2.6565x over previous
//
#include <hip/hip_runtime.h>
#include <hip/hip_bf16.h>
#include <math.h>

typedef unsigned short u16;
typedef __attribute__((ext_vector_type(8))) short  bf16x8;
typedef __attribute__((ext_vector_type(4))) float  f32x4;
typedef __attribute__((ext_vector_type(8))) u16    u16x8;

// ---------------- problem constants ----------------
#define B_      8
#define NT_     16
#define DIM_    768
#define HEADS_  8
#define HD_     96
#define PIX_    1024
#define NTOK_   1040
#define NPAD_   1152              // padded token count (9*128)

// ---------------- workspace layout (byte offsets) ----------------
#define WSO_XCB     0ull            // bf16 xc       (8320,768)   12,779,520 B
#define WSO_WQKV    12779520ull     // bf16 qkv_w    (2304,768)    3,538,944
#define WSO_WPROJ   16318464ull     // bf16 proj_w   (768,768)     1,179,648
#define WSO_QB      17498112ull     // bf16 q  (B,H,1152,96)      14,155,776
#define WSO_KB      31653888ull     // bf16 k  (B,H,1152,96)      14,155,776
#define WSO_VTB     45809664ull     // bf16 vT (B,H,96,1152)      14,155,776
#define WSO_ACATB   59965440ull     // bf16 attn_cat (8320,768)   12,779,520
#define WSO_F32     72744960ull     // fp32 region
// fp32 region offsets (floats)
#define FO_TPOUT    0ull            // (B,NT,DIM)      98,304
#define FO_CHANP    98304ull        // (B,NT,PIX)     131,072
#define FO_RAWCHAN  229376ull       // (B,16,NT,DIM) 1,572,864
#define FO_CHP      1802240ull      // (B,NT,DIM)      98,304
#define FO_FE2      1900544ull      // (B,NT,4,DIM)   393,216
#define FO_STATS    2293760ull      // 1024

// ---------------- output layout (float offsets) ----------------
#define OUT_XOUT   0ull
#define OUT_RAW    6291456ull
#define OUT_ATTN   75513856ull
#define OUT_RAWCH  144736256ull
#define OUT_ATTNCH 146309120ull
#define OUT_QOUT   147881984ull

__device__ __forceinline__ u16 f2b(float f) {
    union { float f; unsigned u; } x; x.f = f;
    unsigned r = x.u + 0x7FFFu + ((x.u >> 16) & 1u);
    return (u16)(r >> 16);
}

// =================== casts ===================
__global__ __launch_bounds__(256) void cast_concat(const float* __restrict__ tp,
                                                   const float* __restrict__ x,
                                                   u16* __restrict__ xcb) {
    size_t idx8 = ((size_t)blockIdx.x * 256 + threadIdx.x) * 8;  // < 8320*768
    int c = idx8 % DIM_;
    int n = (idx8 / DIM_) % NTOK_;
    int b = idx8 / ((size_t)DIM_ * NTOK_);
    const float* s = (n < NT_) ? tp + ((size_t)b * NT_ + n) * DIM_ + c
                               : x + ((size_t)b * PIX_ + (n - NT_)) * DIM_ + c;
    float4 a = *(const float4*)s;
    float4 d = *(const float4*)(s + 4);
    u16x8 r;
    r[0] = f2b(a.x); r[1] = f2b(a.y); r[2] = f2b(a.z); r[3] = f2b(a.w);
    r[4] = f2b(d.x); r[5] = f2b(d.y); r[6] = f2b(d.z); r[7] = f2b(d.w);
    *(u16x8*)(xcb + idx8) = r;
}

__global__ __launch_bounds__(256) void cast8(const float* __restrict__ in,
                                             u16* __restrict__ ob, int n8) {
    int i = blockIdx.x * 256 + threadIdx.x;
    if (i >= n8) return;
    const float* s = in + (size_t)i * 8;
    float4 a = *(const float4*)s;
    float4 d = *(const float4*)(s + 4);
    u16x8 r;
    r[0] = f2b(a.x); r[1] = f2b(a.y); r[2] = f2b(a.z); r[3] = f2b(a.w);
    r[4] = f2b(d.x); r[5] = f2b(d.y); r[6] = f2b(d.z); r[7] = f2b(d.w);
    *(u16x8*)(ob + (size_t)i * 8) = r;
}

// =================== generic bf16 MFMA GEMM: C = A(MxK) @ W(NxK)^T ===================
// 128x128 tile, BK=32, 4 waves (2x2), 16x16x32 MFMA.
// MODE 0: QKV scatter -> q,k bf16 (B,H,1152,96) + vT bf16 (B,H,96,1152)
// MODE 1: scores -> o0[(z*1040+gi)*1040+gj], guarded gi,gj<1040
// MODE 2: proj(+bias) -> split tp_out(o1)/x_out(o0) fp32
template <int MODE>
__global__ __launch_bounds__(256) void gemm_bf16(
    const u16* __restrict__ A, const u16* __restrict__ Bw,
    int lda, int ldb, int K, size_t strA, size_t strB,
    const float* __restrict__ bias,
    float* __restrict__ o0, float* __restrict__ o1,
    u16* __restrict__ oq, u16* __restrict__ ok, u16* __restrict__ ovt) {
    __shared__ u16 As[128][40];
    __shared__ u16 Bs[128][40];
    const int tid = threadIdx.x;
    const int bm = blockIdx.x, bn = blockIdx.y, z = blockIdx.z;
    const u16* Ab = A + strA * z;
    const u16* Bb = Bw + strB * z;
    const int lane = tid & 63, wid = tid >> 6;
    const int ln = lane & 15, hi = lane >> 4;
    const int wr = wid >> 1, wc = wid & 1;
    const int srow = tid >> 1, scol = (tid & 1) * 16;
    f32x4 acc[4][4] = {};
    for (int kt = 0; kt < K; kt += 32) {
        __syncthreads();
        const u16* ga = Ab + (size_t)(bm * 128 + srow) * lda + kt + scol;
        const u16* gb = Bb + (size_t)(bn * 128 + srow) * ldb + kt + scol;
        u16x8 a0 = *(const u16x8*)ga, a1 = *(const u16x8*)(ga + 8);
        u16x8 b0 = *(const u16x8*)gb, b1 = *(const u16x8*)(gb + 8);
        *(u16x8*)&As[srow][scol] = a0;
        *(u16x8*)&As[srow][scol + 8] = a1;
        *(u16x8*)&Bs[srow][scol] = b0;
        *(u16x8*)&Bs[srow][scol + 8] = b1;
        __syncthreads();
        bf16x8 af[4], bfr[4];
#pragma unroll
        for (int m = 0; m < 4; ++m) af[m] = *(const bf16x8*)&As[wr * 64 + m * 16 + ln][hi * 8];
#pragma unroll
        for (int n = 0; n < 4; ++n) bfr[n] = *(const bf16x8*)&Bs[wc * 64 + n * 16 + ln][hi * 8];
#pragma unroll
        for (int m = 0; m < 4; ++m)
#pragma unroll
            for (int n = 0; n < 4; ++n)
                acc[m][n] = __builtin_amdgcn_mfma_f32_16x16x32_bf16(af[m], bfr[n], acc[m][n], 0, 0, 0);
    }
#pragma unroll
    for (int m = 0; m < 4; ++m) {
#pragma unroll
        for (int n = 0; n < 4; ++n) {
#pragma unroll
            for (int j = 0; j < 4; ++j) {
                int gm = bm * 128 + wr * 64 + m * 16 + hi * 4 + j;
                int gn = bn * 128 + wc * 64 + n * 16 + ln;
                float v = acc[m][n][j];
                if (MODE == 0) {
                    int b = gm / NTOK_, nn = gm - b * NTOK_;
                    int s = gn / DIM_, rem = gn - s * DIM_;
                    int h = rem / HD_, d = rem - h * HD_;
                    u16 hv = f2b(v);
                    if (s == 0)
                        oq[(((size_t)b * HEADS_ + h) * NPAD_ + nn) * HD_ + d] = hv;
                    else if (s == 1)
                        ok[(((size_t)b * HEADS_ + h) * NPAD_ + nn) * HD_ + d] = hv;
                    else
                        ovt[(((size_t)b * HEADS_ + h) * HD_ + d) * NPAD_ + nn] = hv;
                } else if (MODE == 1) {
                    if (gm < NTOK_ && gn < NTOK_)
                        o0[((size_t)z * NTOK_ + gm) * NTOK_ + gn] = v;
                } else {
                    v += bias[gn];
                    int b = gm / NTOK_, nn = gm - b * NTOK_;
                    if (nn < NT_) o1[((size_t)b * NT_ + nn) * DIM_ + gn] = v;
                    else          o0[((size_t)b * PIX_ + (nn - NT_)) * DIM_ + gn] = v;
                }
            }
        }
    }
}

// =================== PV: attn(fp32, cast in staging) @ vT -> attn_cat bf16 ===================
__global__ __launch_bounds__(256) void pv_bf16(const float* __restrict__ attn,
                                               const u16* __restrict__ vtb,
                                               u16* __restrict__ acat) {
    __shared__ u16 As[128][40];
    __shared__ u16 Bs[96][40];
    const int tid = threadIdx.x;
    const int bi = blockIdx.x, z = blockIdx.y;
    const int lane = tid & 63, wid = tid >> 6;
    const int ln = lane & 15, hi = lane >> 4;
    const int wr = wid >> 1, wc = wid & 1;
    const float* ap = attn + (size_t)z * NTOK_ * NTOK_;
    const u16* vp = vtb + (size_t)z * HD_ * NPAD_;
    f32x4 acc[4][3] = {};
    for (int kt = 0; kt < 1056; kt += 32) {
        __syncthreads();
        {   // A stage: P fp32 -> bf16, guarded
            int row = tid >> 1, half = tid & 1;
            int gi = bi * 128 + row;
            int kb = kt + half * 16;
            float f[16];
#pragma unroll
            for (int q = 0; q < 4; ++q) {
                float4 v4 = {0.f, 0.f, 0.f, 0.f};
                if (gi < NTOK_ && kb + q * 4 < NTOK_)
                    v4 = *(const float4*)(ap + (size_t)gi * NTOK_ + kb + q * 4);
                f[q * 4 + 0] = v4.x; f[q * 4 + 1] = v4.y;
                f[q * 4 + 2] = v4.z; f[q * 4 + 3] = v4.w;
            }
            u16x8 r0, r1;
#pragma unroll
            for (int q = 0; q < 8; ++q) { r0[q] = f2b(f[q]); r1[q] = f2b(f[8 + q]); }
            *(u16x8*)&As[row][half * 16] = r0;
            *(u16x8*)&As[row][half * 16 + 8] = r1;
        }
        if (tid < 192) {  // B stage: vT rows (96 x 32)
            int row = tid >> 1, half = tid & 1;
            const u16* gb = vp + (size_t)row * NPAD_ + kt + half * 16;
            *(u16x8*)&Bs[row][half * 16] = *(const u16x8*)gb;
            *(u16x8*)&Bs[row][half * 16 + 8] = *(const u16x8*)(gb + 8);
        }
        __syncthreads();
        bf16x8 af[4], bfr[3];
#pragma unroll
        for (int m = 0; m < 4; ++m) af[m] = *(const bf16x8*)&As[wr * 64 + m * 16 + ln][hi * 8];
#pragma unroll
        for (int n = 0; n < 3; ++n) bfr[n] = *(const bf16x8*)&Bs[wc * 48 + n * 16 + ln][hi * 8];
#pragma unroll
        for (int m = 0; m < 4; ++m)
#pragma unroll
            for (int n = 0; n < 3; ++n)
                acc[m][n] = __builtin_amdgcn_mfma_f32_16x16x32_bf16(af[m], bfr[n], acc[m][n], 0, 0, 0);
    }
    int b = z >> 3, h = z & 7;
#pragma unroll
    for (int m = 0; m < 4; ++m)
#pragma unroll
        for (int n = 0; n < 3; ++n)
#pragma unroll
            for (int j = 0; j < 4; ++j) {
                int gi = bi * 128 + wr * 64 + m * 16 + hi * 4 + j;
                if (gi < NTOK_) {
                    int gd = wc * 48 + n * 16 + ln;
                    acat[((size_t)b * NTOK_ + gi) * DIM_ + h * HD_ + gd] = f2b(acc[m][n][j]);
                }
            }
}

// =================== fp32 tiled SGEMM (small chan GEMMs): C = A @ W^T + bias ===================
__global__ __launch_bounds__(256) void sgemm_nt(const float* __restrict__ A,
                                                const float* __restrict__ Bw,
                                                const float* __restrict__ bias,
                                                float* __restrict__ C0,
                                                int M, int Nn, int K) {
    __shared__ float As[16][65];
    __shared__ float Bs[16][65];
    int bm = blockIdx.x, bn = blockIdx.y;
    int tid = threadIdx.x;
    int tx = tid % 16, ty = tid / 16;
    int arow = bm * 64, bcol = bn * 64;
    float acc[4][4] = {};
    for (int kt = 0; kt < K; kt += 16) {
        for (int l = tid; l < 64 * 16; l += 256) {
            int r = l / 16, c = l % 16;
            As[c][r] = A[(size_t)(arow + r) * K + kt + c];
            Bs[c][r] = Bw[(size_t)(bcol + r) * K + kt + c];
        }
        __syncthreads();
#pragma unroll
        for (int kk = 0; kk < 16; ++kk) {
            float a[4], b[4];
#pragma unroll
            for (int i = 0; i < 4; ++i) a[i] = As[kk][i * 16 + ty];
#pragma unroll
            for (int j = 0; j < 4; ++j) b[j] = Bs[kk][j * 16 + tx];
#pragma unroll
            for (int i = 0; i < 4; ++i)
#pragma unroll
                for (int j = 0; j < 4; ++j) acc[i][j] += a[i] * b[j];
        }
        __syncthreads();
    }
#pragma unroll
    for (int i = 0; i < 4; ++i)
#pragma unroll
        for (int j = 0; j < 4; ++j) {
            int m = arow + i * 16 + ty;
            int n = bcol + j * 16 + tx;
            C0[(size_t)m * Nn + n] = acc[i][j] + (bias ? bias[n] : 0.f);
        }
}

// =================== spa softmax (row length 1040) ===================
__global__ __launch_bounds__(256) void spa_softmax(const float* __restrict__ raw,
                                                   float* __restrict__ attn) {
    size_t row = blockIdx.x;
    const float* rp = raw + row * NTOK_;
    float* ap = attn + row * NTOK_;
    int tid = threadIdx.x;
    const float scale = 0.1020620726159658f;  // 96^-0.5
    float vals[5];
    float m = -INFINITY;
#pragma unroll
    for (int i = 0; i < 5; ++i) {
        int idx = tid + i * 256;
        vals[i] = (idx < NTOK_) ? rp[idx] * scale : -INFINITY;
        m = fmaxf(m, vals[i]);
    }
    __shared__ float redm[4], reds[4];
    for (int off = 32; off; off >>= 1) m = fmaxf(m, __shfl_xor(m, off));
    if ((tid & 63) == 0) redm[tid >> 6] = m;
    __syncthreads();
    m = fmaxf(fmaxf(redm[0], redm[1]), fmaxf(redm[2], redm[3]));
    float s = 0.f;
#pragma unroll
    for (int i = 0; i < 5; ++i) {
        int idx = tid + i * 256;
        if (idx < NTOK_) { vals[i] = __expf(vals[i] - m); s += vals[i]; }
    }
    for (int off = 32; off; off >>= 1) s += __shfl_xor(s, off);
    if ((tid & 63) == 0) reds[tid >> 6] = s;
    __syncthreads();
    s = reds[0] + reds[1] + reds[2] + reds[3];
    float inv = 1.f / s;
#pragma unroll
    for (int i = 0; i < 5; ++i) {
        int idx = tid + i * 256;
        if (idx < NTOK_) ap[idx] = vals[i] * inv;
    }
}

// =================== windowed channel scores ===================
__global__ __launch_bounds__(256) void chan_scores(const float* __restrict__ chanp,
                                                   const float* __restrict__ x,
                                                   float* __restrict__ rawchan_ws,
                                                   float* __restrict__ out_raw) {
    int blk = blockIdx.x;  // b*16 + w
    int b = blk / 16, w = blk % 16;
    int nh = w / 4, nw = w % 4;
    __shared__ float qp[16][65];
    __shared__ float xs[64][17];
    int tid = threadIdx.x;
    for (int l = tid; l < 16 * 64; l += 256) {
        int t = l / 64, d = l % 64;
        int wh = d / 8, ww = d % 8;
        int pix = (nh * 8 + wh) * 32 + nw * 8 + ww;
        qp[t][d] = chanp[((size_t)b * NT_ + t) * PIX_ + pix];
    }
    __syncthreads();
    int t = tid % 16, cl = tid / 16;
    for (int cc = 0; cc < 48; ++cc) {
        for (int l = tid; l < 64 * 16; l += 256) {
            int d = l / 16, c2 = l % 16;
            int wh = d / 8, ww = d % 8;
            int pix = (nh * 8 + wh) * 32 + nw * 8 + ww;
            xs[d][c2] = x[((size_t)b * PIX_ + pix) * DIM_ + cc * 16 + c2];
        }
        __syncthreads();
        float acc = 0.f;
#pragma unroll
        for (int d = 0; d < 64; ++d) acc += qp[t][d] * xs[d][cl];
        int c = cc * 16 + cl;
        rawchan_ws[(((size_t)b * 16 + w) * NT_ + t) * DIM_ + c] = acc;
        out_raw[(((size_t)b * NT_ + t) * DIM_ + c) * 16 + w] = acc;
        __syncthreads();
    }
}

// =================== chan softmax over c (768), scattered write ===================
__global__ __launch_bounds__(256) void chan_softmax(const float* __restrict__ rawchan_ws,
                                                    float* __restrict__ out_attn) {
    int row = blockIdx.x;  // (b*16+w)*16 + t
    int b = row / 256;
    int w = (row / 16) % 16;
    int t = row % 16;
    const float* rp = rawchan_ws + (size_t)row * DIM_;
    int tid = threadIdx.x;
    float vals[3];
    float m = -INFINITY;
#pragma unroll
    for (int i = 0; i < 3; ++i) {
        vals[i] = rp[tid + i * 256] * 0.125f;
        m = fmaxf(m, vals[i]);
    }
    __shared__ float redm[4], reds[4];
    for (int off = 32; off; off >>= 1) m = fmaxf(m, __shfl_xor(m, off));
    if ((tid & 63) == 0) redm[tid >> 6] = m;
    __syncthreads();
    m = fmaxf(fmaxf(redm[0], redm[1]), fmaxf(redm[2], redm[3]));
    float s = 0.f;
#pragma unroll
    for (int i = 0; i < 3; ++i) { vals[i] = __expf(vals[i] - m); s += vals[i]; }
    for (int off = 32; off; off >>= 1) s += __shfl_xor(s, off);
    if ((tid & 63) == 0) reds[tid >> 6] = s;
    __syncthreads();
    s = reds[0] + reds[1] + reds[2] + reds[3];
    float inv = 1.f / s;
#pragma unroll
    for (int i = 0; i < 3; ++i) {
        int c = tid + i * 256;
        out_attn[(((size_t)b * NT_ + t) * DIM_ + c) * 16 + w] = vals[i] * inv;
    }
}

// =================== quaternion double conv (per (b,t) block) ===================
__global__ __launch_bounds__(256) void quat_conv(const float* __restrict__ tp,
                                                 const float* __restrict__ tpo,
                                                 const float* __restrict__ chp,
                                                 const float* __restrict__ qf_r, const float* __restrict__ qf_i,
                                                 const float* __restrict__ qf_j, const float* __restrict__ qf_k,
                                                 const float* __restrict__ qf_b,
                                                 const float* __restrict__ dqf_r, const float* __restrict__ dqf_i,
                                                 const float* __restrict__ dqf_j, const float* __restrict__ dqf_k,
                                                 const float* __restrict__ dqf_b,
                                                 float* __restrict__ fe2_out,
                                                 float* __restrict__ partials) {
    int blk = blockIdx.x;  // b*16 + t
    int b = blk / NT_, t = blk % NT_;
    __shared__ float w1[8][4][3];
    __shared__ float w2[8][4][3];
    __shared__ float w2c[4][8][3];
    __shared__ float qs[4][770];
    __shared__ float fs[8][770];
    __shared__ float wsum[4][4], wsq[4][4];
    int tid = threadIdx.x;
    if (tid < 96) {
        int o = tid / 12, rest = tid % 12, ic = rest / 3, tap = rest % 3;
        int g = o / 2, oo = o % 2;
        const int   cidx[4][4] = {{0, 1, 2, 3}, {1, 0, 3, 2}, {2, 3, 0, 1}, {3, 2, 1, 0}};
        const float csgn[4][4] = {{1, -1, -1, -1}, {1, 1, -1, 1}, {1, 1, 1, -1}, {1, -1, 1, 1}};
        const float* s1[4] = {qf_r, qf_i, qf_j, qf_k};
        const float* s2[4] = {dqf_r, dqf_i, dqf_j, dqf_k};
        w1[o][ic][tap] = csgn[g][ic] * s1[cidx[g][ic]][oo * 3 + tap];
        w2[o][ic][tap] = csgn[g][ic] * s2[cidx[g][ic]][oo * 3 + tap];
    }
    for (int l = tid; l < DIM_; l += 256) {
        size_t base = ((size_t)b * NT_ + t) * DIM_ + l;
        qs[0][1 + l] = 0.f;
        qs[1][1 + l] = tp[base];
        qs[2][1 + l] = tpo[base];
        qs[3][1 + l] = chp[base];
    }
    if (tid < 4) { qs[tid][0] = 0.f; qs[tid][769] = 0.f; }
    if (tid < 8) { fs[tid][0] = 0.f; fs[tid][769] = 0.f; }
    __syncthreads();
    if (tid < 96) {
        int o2 = tid / 24, rest = tid % 24, i2 = rest / 3, tap = rest % 3;
        w2c[o2][i2][tap] = w2[i2][o2][2 - tap];
    }
    for (int l = tid; l < DIM_; l += 256) {
#pragma unroll
        for (int o = 0; o < 8; ++o) {
            float a = qf_b[o];
#pragma unroll
            for (int ic = 0; ic < 4; ++ic)
#pragma unroll
                for (int tap = 0; tap < 3; ++tap) a += w1[o][ic][tap] * qs[ic][l + tap];
            fs[o][1 + l] = a;
        }
    }
    __syncthreads();
    float lsum[4] = {}, lsq[4] = {};
    for (int l = tid; l < DIM_; l += 256) {
#pragma unroll
        for (int o2 = 0; o2 < 4; ++o2) {
            float a = dqf_b[o2];
#pragma unroll
            for (int i2 = 0; i2 < 8; ++i2)
#pragma unroll
                for (int tap = 0; tap < 3; ++tap) a += w2c[o2][i2][tap] * fs[i2][l + tap];
            fe2_out[((size_t)blk * 4 + o2) * DIM_ + l] = a;
            lsum[o2] += a;
            lsq[o2] += a * a;
        }
    }
    int wid = tid >> 6;
#pragma unroll
    for (int o2 = 0; o2 < 4; ++o2) {
        float s = lsum[o2], q = lsq[o2];
        for (int off = 32; off; off >>= 1) { s += __shfl_xor(s, off); q += __shfl_xor(q, off); }
        if ((tid & 63) == 0) { wsum[wid][o2] = s; wsq[wid][o2] = q; }
    }
    __syncthreads();
    if (tid < 4) {
        float s = wsum[0][tid] + wsum[1][tid] + wsum[2][tid] + wsum[3][tid];
        float q = wsq[0][tid] + wsq[1][tid] + wsq[2][tid] + wsq[3][tid];
        partials[(size_t)blk * 8 + tid * 2 + 0] = s;
        partials[(size_t)blk * 8 + tid * 2 + 1] = q;
    }
}

// =================== BN + exact GELU + channel mix ===================
__global__ __launch_bounds__(256) void bn_gelu_out(const float* __restrict__ fe2,
                                                   const float* __restrict__ partials,
                                                   const float* __restrict__ bn_g,
                                                   const float* __restrict__ bn_b,
                                                   const float* __restrict__ qfto,
                                                   float* __restrict__ out5) {
    int blk = blockIdx.x;  // b*16 + t
    int b = blk / NT_;
    int tid = threadIdx.x;
    float mean[4], rstd[4], gam[4], bet[4], qw[4];
#pragma unroll
    for (int kk = 0; kk < 4; ++kk) {
        float s = 0.f, q = 0.f;
        for (int t2 = 0; t2 < 16; ++t2) {
            const float* p = partials + ((size_t)(b * NT_ + t2) * 8 + kk * 2);
            s += p[0];
            q += p[1];
        }
        float mu = s * (1.f / 12288.f);
        float var = q * (1.f / 12288.f) - mu * mu;
        mean[kk] = mu;
        rstd[kk] = rsqrtf(var + 1e-5f);
        gam[kk] = bn_g[kk];
        bet[kk] = bn_b[kk];
        qw[kk] = qfto[kk];
    }
    for (int l = tid; l < DIM_; l += 256) {
        float acc = 0.f;
#pragma unroll
        for (int kk = 0; kk < 4; ++kk) {
            float v = fe2[((size_t)blk * 4 + kk) * DIM_ + l];
            float nrm = (v - mean[kk]) * rstd[kk] * gam[kk] + bet[kk];
            float ge = 0.5f * nrm * (1.f + erff(nrm * 0.7071067811865475f));
            acc += ge * qw[kk];
        }
        out5[(size_t)blk * DIM_ + l] = acc;
    }
}

// =================== launch ===================
extern "C" void kernel_launch(void* const* d_in, const int* in_sizes, int n_in,
                              void* d_out, int out_size, void* d_ws, size_t ws_size,
                              hipStream_t stream) {
    const float* x      = (const float*)d_in[0];
    const float* tp     = (const float*)d_in[1];
    const float* qkv_w  = (const float*)d_in[2];
    const float* proj_w = (const float*)d_in[3];
    const float* proj_b = (const float*)d_in[4];
    const float* tt_w   = (const float*)d_in[5];
    const float* tt_b   = (const float*)d_in[6];
    const float* tt1_w  = (const float*)d_in[7];
    const float* tt1_b  = (const float*)d_in[8];
    const float* qf_r   = (const float*)d_in[9];
    const float* qf_i   = (const float*)d_in[10];
    const float* qf_j   = (const float*)d_in[11];
    const float* qf_k   = (const float*)d_in[12];
    const float* qf_b   = (const float*)d_in[13];
    const float* dqf_r  = (const float*)d_in[14];
    const float* dqf_i  = (const float*)d_in[15];
    const float* dqf_j  = (const float*)d_in[16];
    const float* dqf_k  = (const float*)d_in[17];
    const float* dqf_b  = (const float*)d_in[18];
    const float* bn_g   = (const float*)d_in[19];
    const float* bn_b   = (const float*)d_in[20];
    const float* qfto   = (const float*)d_in[21];
    float* out = (float*)d_out;
    char* wsb = (char*)d_ws;

    u16* xcb    = (u16*)(wsb + WSO_XCB);
    u16* wqkvb  = (u16*)(wsb + WSO_WQKV);
    u16* wprojb = (u16*)(wsb + WSO_WPROJ);
    u16* qb     = (u16*)(wsb + WSO_QB);
    u16* kb     = (u16*)(wsb + WSO_KB);
    u16* vtb    = (u16*)(wsb + WSO_VTB);
    u16* acatb  = (u16*)(wsb + WSO_ACATB);
    float* f32r = (float*)(wsb + WSO_F32);
    float* tpout   = f32r + FO_TPOUT;
    float* chanp   = f32r + FO_CHANP;
    float* rawchan = f32r + FO_RAWCHAN;
    float* chpf    = f32r + FO_CHP;
    float* fe2     = f32r + FO_FE2;
    float* stats   = f32r + FO_STATS;

    // casts
    cast_concat<<<3120, 256, 0, stream>>>(tp, x, xcb);
    cast8<<<864, 256, 0, stream>>>(qkv_w, wqkvb, 221184);
    cast8<<<288, 256, 0, stream>>>(proj_w, wprojb, 73728);

    // QKV: (8320x768) @ (2304x768)^T -> q,k,vT bf16
    gemm_bf16<0><<<dim3(65, 18, 1), 256, 0, stream>>>(xcb, wqkvb, 768, 768, 768, 0, 0,
                                                      nullptr, nullptr, nullptr, qb, kb, vtb);
    // scores: per bh (1152x96)@(1152x96)^T -> raw (output 2)
    gemm_bf16<1><<<dim3(9, 9, 64), 256, 0, stream>>>(qb, kb, 96, 96, 96,
                                                     (size_t)NPAD_ * HD_, (size_t)NPAD_ * HD_,
                                                     nullptr, out + OUT_RAW, nullptr,
                                                     nullptr, nullptr, nullptr);
    // softmax (output 3)
    spa_softmax<<<66560, 256, 0, stream>>>(out + OUT_RAW, out + OUT_ATTN);
    // PV -> attn_cat bf16
    pv_bf16<<<dim3(9, 64), 256, 0, stream>>>(out + OUT_ATTN, vtb, acatb);
    // proj -> x_out (output 1) + tp_out
    gemm_bf16<2><<<dim3(65, 6, 1), 256, 0, stream>>>(acatb, wprojb, 768, 768, 768, 0, 0,
                                                     proj_b, out + OUT_XOUT, tpout,
                                                     nullptr, nullptr, nullptr);
    // chan path (fp32, small)
    sgemm_nt<<<dim3(2, 16), 256, 0, stream>>>(tp, tt_w, tt_b, chanp, 128, 1024, 768);
    chan_scores<<<128, 256, 0, stream>>>(chanp, x, rawchan, out + OUT_RAWCH);
    chan_softmax<<<2048, 256, 0, stream>>>(rawchan, out + OUT_ATTNCH);
    sgemm_nt<<<dim3(2, 12), 256, 0, stream>>>(chanp, tt1_w, tt1_b, chpf, 128, 768, 1024);
    // quaternion conv + BN + GELU + mix (output 6)
    quat_conv<<<128, 256, 0, stream>>>(tp, tpout, chpf,
                                       qf_r, qf_i, qf_j, qf_k, qf_b,
                                       dqf_r, dqf_i, dqf_j, dqf_k, dqf_b,
                                       fe2, stats);
    bn_gelu_out<<<128, 256, 0, stream>>>(fe2, stats, bn_g, bn_b, qfto, out + OUT_QOUT);
}

// Round 3
// 829.077 us; speedup vs baseline: 2.8112x; 1.0582x over previous
//
#include <hip/hip_runtime.h>
#include <hip/hip_bf16.h>
#include <math.h>

typedef unsigned short u16;
typedef __attribute__((ext_vector_type(8))) short  bf16x8;
typedef __attribute__((ext_vector_type(4))) float  f32x4;
typedef __attribute__((ext_vector_type(8))) u16    u16x8;
typedef __attribute__((ext_vector_type(4))) u16    u16x4;

// ---------------- problem constants ----------------
#define B_      8
#define NT_     16
#define DIM_    768
#define HEADS_  8
#define HD_     96
#define PIX_    1024
#define NTOK_   1040
#define NPAD_   1152              // padded token count (9*128)

// ---------------- workspace layout (byte offsets) ----------------
#define WSO_XCB     0ull            // bf16 xc       (8320,768)   12,779,520 B
#define WSO_WQKV    12779520ull     // bf16 qkv_w    (2304,768)    3,538,944
#define WSO_WPROJ   16318464ull     // bf16 proj_w   (768,768)     1,179,648
#define WSO_QB      17498112ull     // bf16 q  (B,H,1152,96)      14,155,776
#define WSO_KB      31653888ull     // bf16 k  (B,H,1152,96)      14,155,776
#define WSO_VB      45809664ull     // bf16 v  (B,H,1152,96)      14,155,776
#define WSO_VTB     59965440ull     // bf16 vT (B,H,96,1152)      14,155,776
#define WSO_ACATB   74121216ull     // bf16 attn_cat (8320,768)   12,779,520
#define WSO_F32     86900736ull     // fp32 region
// fp32 region offsets (floats)
#define FO_TPOUT    0ull            // (B,NT,DIM)      98,304
#define FO_CHANP    98304ull        // (B,NT,PIX)     131,072
#define FO_RAWCHAN  229376ull       // (B,16,NT,DIM) 1,572,864
#define FO_CHP      1802240ull      // (B,NT,DIM)      98,304
#define FO_FE2      1900544ull      // (B,NT,4,DIM)   393,216
#define FO_STATS    2293760ull      // 1024

// ---------------- output layout (float offsets) ----------------
#define OUT_XOUT   0ull
#define OUT_RAW    6291456ull
#define OUT_ATTN   75513856ull
#define OUT_RAWCH  144736256ull
#define OUT_ATTNCH 146309120ull
#define OUT_QOUT   147881984ull

__device__ __forceinline__ u16 f2b(float f) {
    union { float f; unsigned u; } x; x.f = f;
    unsigned r = x.u + 0x7FFFu + ((x.u >> 16) & 1u);
    return (u16)(r >> 16);
}
__device__ __forceinline__ u16 f2b_fast(float f) {
    __hip_bfloat16 h = __float2bfloat16(f);   // compiler can pack into v_cvt_pk_bf16_f32
    return __builtin_bit_cast(u16, h);
}

// =================== casts ===================
__global__ __launch_bounds__(256) void cast_concat(const float* __restrict__ tp,
                                                   const float* __restrict__ x,
                                                   u16* __restrict__ xcb) {
    size_t idx8 = ((size_t)blockIdx.x * 256 + threadIdx.x) * 8;  // < 8320*768
    int c = idx8 % DIM_;
    int n = (idx8 / DIM_) % NTOK_;
    int b = idx8 / ((size_t)DIM_ * NTOK_);
    const float* s = (n < NT_) ? tp + ((size_t)b * NT_ + n) * DIM_ + c
                               : x + ((size_t)b * PIX_ + (n - NT_)) * DIM_ + c;
    float4 a = *(const float4*)s;
    float4 d = *(const float4*)(s + 4);
    u16x8 r;
    r[0] = f2b(a.x); r[1] = f2b(a.y); r[2] = f2b(a.z); r[3] = f2b(a.w);
    r[4] = f2b(d.x); r[5] = f2b(d.y); r[6] = f2b(d.z); r[7] = f2b(d.w);
    *(u16x8*)(xcb + idx8) = r;
}

__global__ __launch_bounds__(256) void cast8(const float* __restrict__ in,
                                             u16* __restrict__ ob, int n8) {
    int i = blockIdx.x * 256 + threadIdx.x;
    if (i >= n8) return;
    const float* s = in + (size_t)i * 8;
    float4 a = *(const float4*)s;
    float4 d = *(const float4*)(s + 4);
    u16x8 r;
    r[0] = f2b(a.x); r[1] = f2b(a.y); r[2] = f2b(a.z); r[3] = f2b(a.w);
    r[4] = f2b(d.x); r[5] = f2b(d.y); r[6] = f2b(d.z); r[7] = f2b(d.w);
    *(u16x8*)(ob + (size_t)i * 8) = r;
}

// =================== generic bf16 MFMA GEMM: C = A(MxK) @ W(NxK)^T ===================
// 128x128 tile, BK=32, 4 waves (2x2), 16x16x32 MFMA.
// MODE 0: QKV scatter -> q,k,v bf16 row-major (B,H,1152,96)
// MODE 1: scores -> o0[(z*1040+gi)*1040+gj], guarded gi,gj<1040
// MODE 2: proj(+bias) -> split tp_out(o1)/x_out(o0) fp32
template <int MODE>
__global__ __launch_bounds__(256) void gemm_bf16(
    const u16* __restrict__ A, const u16* __restrict__ Bw,
    int lda, int ldb, int K, size_t strA, size_t strB,
    const float* __restrict__ bias,
    float* __restrict__ o0, float* __restrict__ o1,
    u16* __restrict__ oq, u16* __restrict__ ok, u16* __restrict__ ov) {
    __shared__ u16 As[128][40];
    __shared__ u16 Bs[128][40];
    const int tid = threadIdx.x;
    const int bm = blockIdx.x, bn = blockIdx.y, z = blockIdx.z;
    const u16* Ab = A + strA * z;
    const u16* Bb = Bw + strB * z;
    const int lane = tid & 63, wid = tid >> 6;
    const int ln = lane & 15, hi = lane >> 4;
    const int wr = wid >> 1, wc = wid & 1;
    const int srow = tid >> 1, scol = (tid & 1) * 16;
    f32x4 acc[4][4] = {};
    for (int kt = 0; kt < K; kt += 32) {
        __syncthreads();
        const u16* ga = Ab + (size_t)(bm * 128 + srow) * lda + kt + scol;
        const u16* gb = Bb + (size_t)(bn * 128 + srow) * ldb + kt + scol;
        u16x8 a0 = *(const u16x8*)ga, a1 = *(const u16x8*)(ga + 8);
        u16x8 b0 = *(const u16x8*)gb, b1 = *(const u16x8*)(gb + 8);
        *(u16x8*)&As[srow][scol] = a0;
        *(u16x8*)&As[srow][scol + 8] = a1;
        *(u16x8*)&Bs[srow][scol] = b0;
        *(u16x8*)&Bs[srow][scol + 8] = b1;
        __syncthreads();
        bf16x8 af[4], bfr[4];
#pragma unroll
        for (int m = 0; m < 4; ++m) af[m] = *(const bf16x8*)&As[wr * 64 + m * 16 + ln][hi * 8];
#pragma unroll
        for (int n = 0; n < 4; ++n) bfr[n] = *(const bf16x8*)&Bs[wc * 64 + n * 16 + ln][hi * 8];
#pragma unroll
        for (int m = 0; m < 4; ++m)
#pragma unroll
            for (int n = 0; n < 4; ++n)
                acc[m][n] = __builtin_amdgcn_mfma_f32_16x16x32_bf16(af[m], bfr[n], acc[m][n], 0, 0, 0);
    }
#pragma unroll
    for (int m = 0; m < 4; ++m) {
#pragma unroll
        for (int n = 0; n < 4; ++n) {
#pragma unroll
            for (int j = 0; j < 4; ++j) {
                int gm = bm * 128 + wr * 64 + m * 16 + hi * 4 + j;
                int gn = bn * 128 + wc * 64 + n * 16 + ln;
                float v = acc[m][n][j];
                if (MODE == 0) {
                    int b = gm / NTOK_, nn = gm - b * NTOK_;
                    int s = gn / DIM_, rem = gn - s * DIM_;
                    int h = rem / HD_, d = rem - h * HD_;
                    u16 hv = f2b(v);
                    u16* dst = (s == 0) ? oq : (s == 1) ? ok : ov;
                    dst[(((size_t)b * HEADS_ + h) * NPAD_ + nn) * HD_ + d] = hv;
                } else if (MODE == 1) {
                    if (gm < NTOK_ && gn < NTOK_)
                        o0[((size_t)z * NTOK_ + gm) * NTOK_ + gn] = v;
                } else {
                    v += bias[gn];
                    int b = gm / NTOK_, nn = gm - b * NTOK_;
                    if (nn < NT_) o1[((size_t)b * NT_ + nn) * DIM_ + gn] = v;
                    else          o0[((size_t)b * PIX_ + (nn - NT_)) * DIM_ + gn] = v;
                }
            }
        }
    }
}

// =================== v (B,H,1152,96) -> vT (B,H,96,1152) ===================
__global__ __launch_bounds__(256) void transpose_v(const u16* __restrict__ vb,
                                                   u16* __restrict__ vtb) {
    __shared__ u16 t[32][34];
    int bi = blockIdx.x;   // 36 row tiles (token dim)
    int bj = blockIdx.y;   // 3 col tiles (d dim)
    int z  = blockIdx.z;   // 64
    const u16* ib = vb + (size_t)z * NPAD_ * HD_;
    u16* ob = vtb + (size_t)z * HD_ * NPAD_;
    int tid = threadIdx.x;
    int r = tid >> 3, c = (tid & 7) * 4;
    *(u16x4*)&t[r][c] = *(const u16x4*)(ib + (size_t)(bi * 32 + r) * HD_ + bj * 32 + c);
    __syncthreads();
    u16x4 o;
    o[0] = t[c + 0][r]; o[1] = t[c + 1][r]; o[2] = t[c + 2][r]; o[3] = t[c + 3][r];
    *(u16x4*)(ob + (size_t)(bj * 32 + r) * NPAD_ + bi * 32 + c) = o;
}

// =================== PV: attn(fp32 -> bf16 in staging) @ vT -> attn_cat bf16 ===================
// 64x96 tile per block, grid (17, 64). K padded to 1056 (cols >=1040 zeroed).
__global__ __launch_bounds__(256) void pv_bf16(const float* __restrict__ attn,
                                               const u16* __restrict__ vtb,
                                               u16* __restrict__ acat) {
    __shared__ u16 As[64][40];
    __shared__ u16 Bs[96][40];
    const int tid = threadIdx.x;
    const int bi = blockIdx.x, z = blockIdx.y;
    const int lane = tid & 63, wid = tid >> 6;
    const int ln = lane & 15, hi = lane >> 4;
    const int wr = wid >> 1, wc = wid & 1;
    const float* ap = attn + (size_t)z * NTOK_ * NTOK_;
    const u16* vp = vtb + (size_t)z * HD_ * NPAD_;
    const int arow = tid >> 2, ac0 = (tid & 3) * 8;
    const int gi_s = bi * 64 + arow;
    f32x4 acc[2][3] = {};
    for (int kt = 0; kt < 1056; kt += 32) {
        __syncthreads();
        {   // A stage: 64 x 32 fp32 -> bf16 (col multiple of 8; 1040 % 8 == 0)
            int col = kt + ac0;
            float4 v0 = {0.f, 0.f, 0.f, 0.f}, v1 = {0.f, 0.f, 0.f, 0.f};
            if (gi_s < NTOK_ && col < NTOK_) {
                const float* p = ap + (size_t)gi_s * NTOK_ + col;
                v0 = *(const float4*)p;
                v1 = *(const float4*)(p + 4);
            }
            u16x8 r;
            r[0] = f2b_fast(v0.x); r[1] = f2b_fast(v0.y);
            r[2] = f2b_fast(v0.z); r[3] = f2b_fast(v0.w);
            r[4] = f2b_fast(v1.x); r[5] = f2b_fast(v1.y);
            r[6] = f2b_fast(v1.z); r[7] = f2b_fast(v1.w);
            *(u16x8*)&As[arow][ac0] = r;
        }
        if (tid < 192) {  // B stage: vT 96 rows x 32 cols
            int row = tid >> 1, half = tid & 1;
            const u16* gb = vp + (size_t)row * NPAD_ + kt + half * 16;
            *(u16x8*)&Bs[row][half * 16] = *(const u16x8*)gb;
            *(u16x8*)&Bs[row][half * 16 + 8] = *(const u16x8*)(gb + 8);
        }
        __syncthreads();
        bf16x8 af[2], bfr[3];
#pragma unroll
        for (int m = 0; m < 2; ++m) af[m] = *(const bf16x8*)&As[wr * 32 + m * 16 + ln][hi * 8];
#pragma unroll
        for (int n = 0; n < 3; ++n) bfr[n] = *(const bf16x8*)&Bs[wc * 48 + n * 16 + ln][hi * 8];
#pragma unroll
        for (int m = 0; m < 2; ++m)
#pragma unroll
            for (int n = 0; n < 3; ++n)
                acc[m][n] = __builtin_amdgcn_mfma_f32_16x16x32_bf16(af[m], bfr[n], acc[m][n], 0, 0, 0);
    }
    int b = z >> 3, h = z & 7;
#pragma unroll
    for (int m = 0; m < 2; ++m)
#pragma unroll
        for (int n = 0; n < 3; ++n)
#pragma unroll
            for (int j = 0; j < 4; ++j) {
                int gi = bi * 64 + wr * 32 + m * 16 + hi * 4 + j;
                if (gi < NTOK_) {
                    int gd = wc * 48 + n * 16 + ln;
                    acat[((size_t)b * NTOK_ + gi) * DIM_ + h * HD_ + gd] = f2b(acc[m][n][j]);
                }
            }
}

// =================== fp32 tiled SGEMM (small chan GEMMs): C = A @ W^T + bias ===================
__global__ __launch_bounds__(256) void sgemm_nt(const float* __restrict__ A,
                                                const float* __restrict__ Bw,
                                                const float* __restrict__ bias,
                                                float* __restrict__ C0,
                                                int M, int Nn, int K) {
    __shared__ float As[16][65];
    __shared__ float Bs[16][65];
    int bm = blockIdx.x, bn = blockIdx.y;
    int tid = threadIdx.x;
    int tx = tid % 16, ty = tid / 16;
    int arow = bm * 64, bcol = bn * 64;
    float acc[4][4] = {};
    for (int kt = 0; kt < K; kt += 16) {
        for (int l = tid; l < 64 * 16; l += 256) {
            int r = l / 16, c = l % 16;
            As[c][r] = A[(size_t)(arow + r) * K + kt + c];
            Bs[c][r] = Bw[(size_t)(bcol + r) * K + kt + c];
        }
        __syncthreads();
#pragma unroll
        for (int kk = 0; kk < 16; ++kk) {
            float a[4], b[4];
#pragma unroll
            for (int i = 0; i < 4; ++i) a[i] = As[kk][i * 16 + ty];
#pragma unroll
            for (int j = 0; j < 4; ++j) b[j] = Bs[kk][j * 16 + tx];
#pragma unroll
            for (int i = 0; i < 4; ++i)
#pragma unroll
                for (int j = 0; j < 4; ++j) acc[i][j] += a[i] * b[j];
        }
        __syncthreads();
    }
#pragma unroll
    for (int i = 0; i < 4; ++i)
#pragma unroll
        for (int j = 0; j < 4; ++j) {
            int m = arow + i * 16 + ty;
            int n = bcol + j * 16 + tx;
            C0[(size_t)m * Nn + n] = acc[i][j] + (bias ? bias[n] : 0.f);
        }
}

// =================== spa softmax (row length 1040) ===================
__global__ __launch_bounds__(256) void spa_softmax(const float* __restrict__ raw,
                                                   float* __restrict__ attn) {
    size_t row = blockIdx.x;
    const float* rp = raw + row * NTOK_;
    float* ap = attn + row * NTOK_;
    int tid = threadIdx.x;
    const float scale = 0.1020620726159658f;  // 96^-0.5
    float vals[5];
    float m = -INFINITY;
#pragma unroll
    for (int i = 0; i < 5; ++i) {
        int idx = tid + i * 256;
        vals[i] = (idx < NTOK_) ? rp[idx] * scale : -INFINITY;
        m = fmaxf(m, vals[i]);
    }
    __shared__ float redm[4], reds[4];
    for (int off = 32; off; off >>= 1) m = fmaxf(m, __shfl_xor(m, off));
    if ((tid & 63) == 0) redm[tid >> 6] = m;
    __syncthreads();
    m = fmaxf(fmaxf(redm[0], redm[1]), fmaxf(redm[2], redm[3]));
    float s = 0.f;
#pragma unroll
    for (int i = 0; i < 5; ++i) {
        int idx = tid + i * 256;
        if (idx < NTOK_) { vals[i] = __expf(vals[i] - m); s += vals[i]; }
    }
    for (int off = 32; off; off >>= 1) s += __shfl_xor(s, off);
    if ((tid & 63) == 0) reds[tid >> 6] = s;
    __syncthreads();
    s = reds[0] + reds[1] + reds[2] + reds[3];
    float inv = 1.f / s;
#pragma unroll
    for (int i = 0; i < 5; ++i) {
        int idx = tid + i * 256;
        if (idx < NTOK_) ap[idx] = vals[i] * inv;
    }
}

// =================== windowed channel scores ===================
__global__ __launch_bounds__(256) void chan_scores(const float* __restrict__ chanp,
                                                   const float* __restrict__ x,
                                                   float* __restrict__ rawchan_ws,
                                                   float* __restrict__ out_raw) {
    int blk = blockIdx.x;  // b*16 + w
    int b = blk / 16, w = blk % 16;
    int nh = w / 4, nw = w % 4;
    __shared__ float qp[16][65];
    __shared__ float xs[64][17];
    int tid = threadIdx.x;
    for (int l = tid; l < 16 * 64; l += 256) {
        int t = l / 64, d = l % 64;
        int wh = d / 8, ww = d % 8;
        int pix = (nh * 8 + wh) * 32 + nw * 8 + ww;
        qp[t][d] = chanp[((size_t)b * NT_ + t) * PIX_ + pix];
    }
    __syncthreads();
    int t = tid % 16, cl = tid / 16;
    for (int cc = 0; cc < 48; ++cc) {
        for (int l = tid; l < 64 * 16; l += 256) {
            int d = l / 16, c2 = l % 16;
            int wh = d / 8, ww = d % 8;
            int pix = (nh * 8 + wh) * 32 + nw * 8 + ww;
            xs[d][c2] = x[((size_t)b * PIX_ + pix) * DIM_ + cc * 16 + c2];
        }
        __syncthreads();
        float acc = 0.f;
#pragma unroll
        for (int d = 0; d < 64; ++d) acc += qp[t][d] * xs[d][cl];
        int c = cc * 16 + cl;
        rawchan_ws[(((size_t)b * 16 + w) * NT_ + t) * DIM_ + c] = acc;
        out_raw[(((size_t)b * NT_ + t) * DIM_ + c) * 16 + w] = acc;
        __syncthreads();
    }
}

// =================== chan softmax over c (768), scattered write ===================
__global__ __launch_bounds__(256) void chan_softmax(const float* __restrict__ rawchan_ws,
                                                    float* __restrict__ out_attn) {
    int row = blockIdx.x;  // (b*16+w)*16 + t
    int b = row / 256;
    int w = (row / 16) % 16;
    int t = row % 16;
    const float* rp = rawchan_ws + (size_t)row * DIM_;
    int tid = threadIdx.x;
    float vals[3];
    float m = -INFINITY;
#pragma unroll
    for (int i = 0; i < 3; ++i) {
        vals[i] = rp[tid + i * 256] * 0.125f;
        m = fmaxf(m, vals[i]);
    }
    __shared__ float redm[4], reds[4];
    for (int off = 32; off; off >>= 1) m = fmaxf(m, __shfl_xor(m, off));
    if ((tid & 63) == 0) redm[tid >> 6] = m;
    __syncthreads();
    m = fmaxf(fmaxf(redm[0], redm[1]), fmaxf(redm[2], redm[3]));
    float s = 0.f;
#pragma unroll
    for (int i = 0; i < 3; ++i) { vals[i] = __expf(vals[i] - m); s += vals[i]; }
    for (int off = 32; off; off >>= 1) s += __shfl_xor(s, off);
    if ((tid & 63) == 0) reds[tid >> 6] = s;
    __syncthreads();
    s = reds[0] + reds[1] + reds[2] + reds[3];
    float inv = 1.f / s;
#pragma unroll
    for (int i = 0; i < 3; ++i) {
        int c = tid + i * 256;
        out_attn[(((size_t)b * NT_ + t) * DIM_ + c) * 16 + w] = vals[i] * inv;
    }
}

// =================== quaternion double conv (per (b,t) block) ===================
__global__ __launch_bounds__(256) void quat_conv(const float* __restrict__ tp,
                                                 const float* __restrict__ tpo,
                                                 const float* __restrict__ chp,
                                                 const float* __restrict__ qf_r, const float* __restrict__ qf_i,
                                                 const float* __restrict__ qf_j, const float* __restrict__ qf_k,
                                                 const float* __restrict__ qf_b,
                                                 const float* __restrict__ dqf_r, const float* __restrict__ dqf_i,
                                                 const float* __restrict__ dqf_j, const float* __restrict__ dqf_k,
                                                 const float* __restrict__ dqf_b,
                                                 float* __restrict__ fe2_out,
                                                 float* __restrict__ partials) {
    int blk = blockIdx.x;  // b*16 + t
    int b = blk / NT_, t = blk % NT_;
    __shared__ float w1[8][4][3];
    __shared__ float w2[8][4][3];
    __shared__ float w2c[4][8][3];
    __shared__ float qs[4][770];
    __shared__ float fs[8][770];
    __shared__ float wsum[4][4], wsq[4][4];
    int tid = threadIdx.x;
    if (tid < 96) {
        int o = tid / 12, rest = tid % 12, ic = rest / 3, tap = rest % 3;
        int g = o / 2, oo = o % 2;
        const int   cidx[4][4] = {{0, 1, 2, 3}, {1, 0, 3, 2}, {2, 3, 0, 1}, {3, 2, 1, 0}};
        const float csgn[4][4] = {{1, -1, -1, -1}, {1, 1, -1, 1}, {1, 1, 1, -1}, {1, -1, 1, 1}};
        const float* s1[4] = {qf_r, qf_i, qf_j, qf_k};
        const float* s2[4] = {dqf_r, dqf_i, dqf_j, dqf_k};
        w1[o][ic][tap] = csgn[g][ic] * s1[cidx[g][ic]][oo * 3 + tap];
        w2[o][ic][tap] = csgn[g][ic] * s2[cidx[g][ic]][oo * 3 + tap];
    }
    for (int l = tid; l < DIM_; l += 256) {
        size_t base = ((size_t)b * NT_ + t) * DIM_ + l;
        qs[0][1 + l] = 0.f;
        qs[1][1 + l] = tp[base];
        qs[2][1 + l] = tpo[base];
        qs[3][1 + l] = chp[base];
    }
    if (tid < 4) { qs[tid][0] = 0.f; qs[tid][769] = 0.f; }
    if (tid < 8) { fs[tid][0] = 0.f; fs[tid][769] = 0.f; }
    __syncthreads();
    if (tid < 96) {
        int o2 = tid / 24, rest = tid % 24, i2 = rest / 3, tap = rest % 3;
        w2c[o2][i2][tap] = w2[i2][o2][2 - tap];
    }
    for (int l = tid; l < DIM_; l += 256) {
#pragma unroll
        for (int o = 0; o < 8; ++o) {
            float a = qf_b[o];
#pragma unroll
            for (int ic = 0; ic < 4; ++ic)
#pragma unroll
                for (int tap = 0; tap < 3; ++tap) a += w1[o][ic][tap] * qs[ic][l + tap];
            fs[o][1 + l] = a;
        }
    }
    __syncthreads();
    float lsum[4] = {}, lsq[4] = {};
    for (int l = tid; l < DIM_; l += 256) {
#pragma unroll
        for (int o2 = 0; o2 < 4; ++o2) {
            float a = dqf_b[o2];
#pragma unroll
            for (int i2 = 0; i2 < 8; ++i2)
#pragma unroll
                for (int tap = 0; tap < 3; ++tap) a += w2c[o2][i2][tap] * fs[i2][l + tap];
            fe2_out[((size_t)blk * 4 + o2) * DIM_ + l] = a;
            lsum[o2] += a;
            lsq[o2] += a * a;
        }
    }
    int wid = tid >> 6;
#pragma unroll
    for (int o2 = 0; o2 < 4; ++o2) {
        float s = lsum[o2], q = lsq[o2];
        for (int off = 32; off; off >>= 1) { s += __shfl_xor(s, off); q += __shfl_xor(q, off); }
        if ((tid & 63) == 0) { wsum[wid][o2] = s; wsq[wid][o2] = q; }
    }
    __syncthreads();
    if (tid < 4) {
        float s = wsum[0][tid] + wsum[1][tid] + wsum[2][tid] + wsum[3][tid];
        float q = wsq[0][tid] + wsq[1][tid] + wsq[2][tid] + wsq[3][tid];
        partials[(size_t)blk * 8 + tid * 2 + 0] = s;
        partials[(size_t)blk * 8 + tid * 2 + 1] = q;
    }
}

// =================== BN + exact GELU + channel mix ===================
__global__ __launch_bounds__(256) void bn_gelu_out(const float* __restrict__ fe2,
                                                   const float* __restrict__ partials,
                                                   const float* __restrict__ bn_g,
                                                   const float* __restrict__ bn_b,
                                                   const float* __restrict__ qfto,
                                                   float* __restrict__ out5) {
    int blk = blockIdx.x;  // b*16 + t
    int b = blk / NT_;
    int tid = threadIdx.x;
    float mean[4], rstd[4], gam[4], bet[4], qw[4];
#pragma unroll
    for (int kk = 0; kk < 4; ++kk) {
        float s = 0.f, q = 0.f;
        for (int t2 = 0; t2 < 16; ++t2) {
            const float* p = partials + ((size_t)(b * NT_ + t2) * 8 + kk * 2);
            s += p[0];
            q += p[1];
        }
        float mu = s * (1.f / 12288.f);
        float var = q * (1.f / 12288.f) - mu * mu;
        mean[kk] = mu;
        rstd[kk] = rsqrtf(var + 1e-5f);
        gam[kk] = bn_g[kk];
        bet[kk] = bn_b[kk];
        qw[kk] = qfto[kk];
    }
    for (int l = tid; l < DIM_; l += 256) {
        float acc = 0.f;
#pragma unroll
        for (int kk = 0; kk < 4; ++kk) {
            float v = fe2[((size_t)blk * 4 + kk) * DIM_ + l];
            float nrm = (v - mean[kk]) * rstd[kk] * gam[kk] + bet[kk];
            float ge = 0.5f * nrm * (1.f + erff(nrm * 0.7071067811865475f));
            acc += ge * qw[kk];
        }
        out5[(size_t)blk * DIM_ + l] = acc;
    }
}

// =================== launch ===================
extern "C" void kernel_launch(void* const* d_in, const int* in_sizes, int n_in,
                              void* d_out, int out_size, void* d_ws, size_t ws_size,
                              hipStream_t stream) {
    const float* x      = (const float*)d_in[0];
    const float* tp     = (const float*)d_in[1];
    const float* qkv_w  = (const float*)d_in[2];
    const float* proj_w = (const float*)d_in[3];
    const float* proj_b = (const float*)d_in[4];
    const float* tt_w   = (const float*)d_in[5];
    const float* tt_b   = (const float*)d_in[6];
    const float* tt1_w  = (const float*)d_in[7];
    const float* tt1_b  = (const float*)d_in[8];
    const float* qf_r   = (const float*)d_in[9];
    const float* qf_i   = (const float*)d_in[10];
    const float* qf_j   = (const float*)d_in[11];
    const float* qf_k   = (const float*)d_in[12];
    const float* qf_b   = (const float*)d_in[13];
    const float* dqf_r  = (const float*)d_in[14];
    const float* dqf_i  = (const float*)d_in[15];
    const float* dqf_j  = (const float*)d_in[16];
    const float* dqf_k  = (const float*)d_in[17];
    const float* dqf_b  = (const float*)d_in[18];
    const float* bn_g   = (const float*)d_in[19];
    const float* bn_b   = (const float*)d_in[20];
    const float* qfto   = (const float*)d_in[21];
    float* out = (float*)d_out;
    char* wsb = (char*)d_ws;

    u16* xcb    = (u16*)(wsb + WSO_XCB);
    u16* wqkvb  = (u16*)(wsb + WSO_WQKV);
    u16* wprojb = (u16*)(wsb + WSO_WPROJ);
    u16* qb     = (u16*)(wsb + WSO_QB);
    u16* kb     = (u16*)(wsb + WSO_KB);
    u16* vb     = (u16*)(wsb + WSO_VB);
    u16* vtb    = (u16*)(wsb + WSO_VTB);
    u16* acatb  = (u16*)(wsb + WSO_ACATB);
    float* f32r = (float*)(wsb + WSO_F32);
    float* tpout   = f32r + FO_TPOUT;
    float* chanp   = f32r + FO_CHANP;
    float* rawchan = f32r + FO_RAWCHAN;
    float* chpf    = f32r + FO_CHP;
    float* fe2     = f32r + FO_FE2;
    float* stats   = f32r + FO_STATS;

    // casts
    cast_concat<<<3120, 256, 0, stream>>>(tp, x, xcb);
    cast8<<<864, 256, 0, stream>>>(qkv_w, wqkvb, 221184);
    cast8<<<288, 256, 0, stream>>>(proj_w, wprojb, 73728);

    // QKV: (8320x768) @ (2304x768)^T -> q,k,v bf16 row-major
    gemm_bf16<0><<<dim3(65, 18, 1), 256, 0, stream>>>(xcb, wqkvb, 768, 768, 768, 0, 0,
                                                      nullptr, nullptr, nullptr, qb, kb, vb);
    // v -> vT
    transpose_v<<<dim3(36, 3, 64), 256, 0, stream>>>(vb, vtb);
    // scores: per bh (1152x96)@(1152x96)^T -> raw (output 2)
    gemm_bf16<1><<<dim3(9, 9, 64), 256, 0, stream>>>(qb, kb, 96, 96, 96,
                                                     (size_t)NPAD_ * HD_, (size_t)NPAD_ * HD_,
                                                     nullptr, out + OUT_RAW, nullptr,
                                                     nullptr, nullptr, nullptr);
    // softmax (output 3)
    spa_softmax<<<66560, 256, 0, stream>>>(out + OUT_RAW, out + OUT_ATTN);
    // PV -> attn_cat bf16
    pv_bf16<<<dim3(17, 64), 256, 0, stream>>>(out + OUT_ATTN, vtb, acatb);
    // proj -> x_out (output 1) + tp_out
    gemm_bf16<2><<<dim3(65, 6, 1), 256, 0, stream>>>(acatb, wprojb, 768, 768, 768, 0, 0,
                                                     proj_b, out + OUT_XOUT, tpout,
                                                     nullptr, nullptr, nullptr);
    // chan path (fp32, small)
    sgemm_nt<<<dim3(2, 16), 256, 0, stream>>>(tp, tt_w, tt_b, chanp, 128, 1024, 768);
    chan_scores<<<128, 256, 0, stream>>>(chanp, x, rawchan, out + OUT_RAWCH);
    chan_softmax<<<2048, 256, 0, stream>>>(rawchan, out + OUT_ATTNCH);
    sgemm_nt<<<dim3(2, 12), 256, 0, stream>>>(chanp, tt1_w, tt1_b, chpf, 128, 768, 1024);
    // quaternion conv + BN + GELU + mix (output 6)
    quat_conv<<<128, 256, 0, stream>>>(tp, tpout, chpf,
                                       qf_r, qf_i, qf_j, qf_k, qf_b,
                                       dqf_r, dqf_i, dqf_j, dqf_k, dqf_b,
                                       fe2, stats);
    bn_gelu_out<<<128, 256, 0, stream>>>(fe2, stats, bn_g, bn_b, qfto, out + OUT_QOUT);
}

// Round 4
// 611.913 us; speedup vs baseline: 3.8089x; 1.3549x over previous
//
#include <hip/hip_runtime.h>
#include <hip/hip_bf16.h>
#include <math.h>

typedef unsigned short u16;
typedef __attribute__((ext_vector_type(8))) short  bf16x8;
typedef __attribute__((ext_vector_type(4))) float  f32x4;
typedef __attribute__((ext_vector_type(8))) u16    u16x8;
typedef __attribute__((ext_vector_type(4))) u16    u16x4;

// ---------------- problem constants ----------------
#define B_      8
#define NT_     16
#define DIM_    768
#define HEADS_  8
#define HD_     96
#define PIX_    1024
#define NTOK_   1040
#define NPAD_   1152

// ---------------- workspace layout (byte offsets) ----------------
#define WSO_XCB     0ull
#define WSO_WQKV    12779520ull
#define WSO_WPROJ   16318464ull
#define WSO_QB      17498112ull
#define WSO_KB      31653888ull
#define WSO_VB      45809664ull
#define WSO_VTB     59965440ull
#define WSO_ACATB   74121216ull
#define WSO_TPB     86900736ull
#define WSO_TTWB    87097344ull
#define WSO_TT1WB   88670208ull
#define WSO_CHANPB  90243072ull
#define WSO_PART    90505216ull    // (64,9,1152) float2  = 5,308,416 B
#define WSO_F32     95813632ull
// fp32 region offsets (floats)
#define FO_TPOUT    0ull           // 98,304
#define FO_RAWCHAN  98304ull       // 1,572,864
#define FO_CHP      1671168ull     // 98,304
#define FO_FE2      1769472ull     // 393,216
#define FO_STATS    2162688ull     // 1024

// ---------------- output layout (float offsets) ----------------
#define OUT_XOUT   0ull
#define OUT_RAW    6291456ull
#define OUT_ATTN   75513856ull
#define OUT_RAWCH  144736256ull
#define OUT_ATTNCH 146309120ull
#define OUT_QOUT   147881984ull

#define SCALE_SPA 0.1020620726159658f   // 96^-0.5

__device__ __forceinline__ u16 f2b(float f) {
    union { float f; unsigned u; } x; x.f = f;
    unsigned r = x.u + 0x7FFFu + ((x.u >> 16) & 1u);
    return (u16)(r >> 16);
}
__device__ __forceinline__ u16 f2b_fast(float f) {
    __hip_bfloat16 h = __float2bfloat16(f);
    return __builtin_bit_cast(u16, h);
}
__device__ __forceinline__ float b2f(u16 h) {
    union { unsigned u; float f; } x; x.u = ((unsigned)h) << 16;
    return x.f;
}

// =================== casts ===================
__global__ __launch_bounds__(256) void cast_concat(const float* __restrict__ tp,
                                                   const float* __restrict__ x,
                                                   u16* __restrict__ xcb) {
    size_t idx8 = ((size_t)blockIdx.x * 256 + threadIdx.x) * 8;
    int c = idx8 % DIM_;
    int n = (idx8 / DIM_) % NTOK_;
    int b = idx8 / ((size_t)DIM_ * NTOK_);
    const float* s = (n < NT_) ? tp + ((size_t)b * NT_ + n) * DIM_ + c
                               : x + ((size_t)b * PIX_ + (n - NT_)) * DIM_ + c;
    float4 a = *(const float4*)s;
    float4 d = *(const float4*)(s + 4);
    u16x8 r;
    r[0] = f2b(a.x); r[1] = f2b(a.y); r[2] = f2b(a.z); r[3] = f2b(a.w);
    r[4] = f2b(d.x); r[5] = f2b(d.y); r[6] = f2b(d.z); r[7] = f2b(d.w);
    *(u16x8*)(xcb + idx8) = r;
}

__global__ __launch_bounds__(256) void cast8(const float* __restrict__ in,
                                             u16* __restrict__ ob, int n8) {
    int i = blockIdx.x * 256 + threadIdx.x;
    if (i >= n8) return;
    const float* s = in + (size_t)i * 8;
    float4 a = *(const float4*)s;
    float4 d = *(const float4*)(s + 4);
    u16x8 r;
    r[0] = f2b(a.x); r[1] = f2b(a.y); r[2] = f2b(a.z); r[3] = f2b(a.w);
    r[4] = f2b(d.x); r[5] = f2b(d.y); r[6] = f2b(d.z); r[7] = f2b(d.w);
    *(u16x8*)(ob + (size_t)i * 8) = r;
}

// =================== generic bf16 MFMA GEMM: C = A(MxK) @ W(NxK)^T ===================
// MODE 0: QKV scatter -> q,k,v bf16 row-major (B,H,1152,96)
// MODE 1: scores -> raw fp32 (guarded) + per-(row,jtile) softmax partials (o1)
// MODE 2: proj(+bias) -> split tp_out(o1)/x_out(o0) fp32
// MODE 3: plain bf16 out (+bias) to oq, stride ldo
// MODE 4: plain fp32 out (+bias) to o0, stride ldo
template <int MODE>
__global__ __launch_bounds__(256) void gemm_bf16(
    const u16* __restrict__ A, const u16* __restrict__ Bw,
    int lda, int ldb, int K, size_t strA, size_t strB,
    const float* __restrict__ bias,
    float* __restrict__ o0, float* __restrict__ o1,
    u16* __restrict__ oq, u16* __restrict__ ok, u16* __restrict__ ov,
    int ldo) {
    __shared__ u16 As[128][40];
    __shared__ u16 Bs[128][40];
    __shared__ float redm[128][2];
    __shared__ float reds[128][2];
    const int tid = threadIdx.x;
    const int bm = blockIdx.x, bn = blockIdx.y, z = blockIdx.z;
    const u16* Ab = A + strA * z;
    const u16* Bb = Bw + strB * z;
    const int lane = tid & 63, wid = tid >> 6;
    const int ln = lane & 15, hi = lane >> 4;
    const int wr = wid >> 1, wc = wid & 1;
    const int srow = tid >> 1, scol = (tid & 1) * 16;
    f32x4 acc[4][4] = {};
    for (int kt = 0; kt < K; kt += 32) {
        __syncthreads();
        const u16* ga = Ab + (size_t)(bm * 128 + srow) * lda + kt + scol;
        const u16* gb = Bb + (size_t)(bn * 128 + srow) * ldb + kt + scol;
        u16x8 a0 = *(const u16x8*)ga, a1 = *(const u16x8*)(ga + 8);
        u16x8 b0 = *(const u16x8*)gb, b1 = *(const u16x8*)(gb + 8);
        *(u16x8*)&As[srow][scol] = a0;
        *(u16x8*)&As[srow][scol + 8] = a1;
        *(u16x8*)&Bs[srow][scol] = b0;
        *(u16x8*)&Bs[srow][scol + 8] = b1;
        __syncthreads();
        bf16x8 af[4], bfr[4];
#pragma unroll
        for (int m = 0; m < 4; ++m) af[m] = *(const bf16x8*)&As[wr * 64 + m * 16 + ln][hi * 8];
#pragma unroll
        for (int n = 0; n < 4; ++n) bfr[n] = *(const bf16x8*)&Bs[wc * 64 + n * 16 + ln][hi * 8];
#pragma unroll
        for (int m = 0; m < 4; ++m)
#pragma unroll
            for (int n = 0; n < 4; ++n)
                acc[m][n] = __builtin_amdgcn_mfma_f32_16x16x32_bf16(af[m], bfr[n], acc[m][n], 0, 0, 0);
    }
#pragma unroll
    for (int m = 0; m < 4; ++m) {
#pragma unroll
        for (int n = 0; n < 4; ++n) {
#pragma unroll
            for (int j = 0; j < 4; ++j) {
                int gm = bm * 128 + wr * 64 + m * 16 + hi * 4 + j;
                int gn = bn * 128 + wc * 64 + n * 16 + ln;
                float v = acc[m][n][j];
                if (MODE == 0) {
                    int b = gm / NTOK_, nn = gm - b * NTOK_;
                    int s = gn / DIM_, rem = gn - s * DIM_;
                    int h = rem / HD_, d = rem - h * HD_;
                    u16 hv = f2b(v);
                    u16* dst = (s == 0) ? oq : (s == 1) ? ok : ov;
                    dst[(((size_t)b * HEADS_ + h) * NPAD_ + nn) * HD_ + d] = hv;
                } else if (MODE == 1) {
                    if (gm < NTOK_ && gn < NTOK_)
                        o0[((size_t)z * NTOK_ + gm) * NTOK_ + gn] = v;
                } else if (MODE == 2) {
                    v += bias[gn];
                    int b = gm / NTOK_, nn = gm - b * NTOK_;
                    if (nn < NT_) o1[((size_t)b * NT_ + nn) * DIM_ + gn] = v;
                    else          o0[((size_t)b * PIX_ + (nn - NT_)) * DIM_ + gn] = v;
                } else if (MODE == 3) {
                    oq[(size_t)gm * ldo + gn] = f2b(v + bias[gn]);
                } else {
                    o0[(size_t)gm * ldo + gn] = v + bias[gn];
                }
            }
        }
    }
    if (MODE == 1) {
        // per-(row, this j-tile) softmax partials over the 128 cols of this tile
#pragma unroll
        for (int m = 0; m < 4; ++m) {
#pragma unroll
            for (int j = 0; j < 4; ++j) {
                float v[4];
                float mx = -INFINITY;
#pragma unroll
                for (int n = 0; n < 4; ++n) {
                    int gn = bn * 128 + wc * 64 + n * 16 + ln;
                    v[n] = (gn < NTOK_) ? acc[m][n][j] * SCALE_SPA : -INFINITY;
                    mx = fmaxf(mx, v[n]);
                }
#pragma unroll
                for (int off = 1; off < 16; off <<= 1) mx = fmaxf(mx, __shfl_xor(mx, off));
                float s = 0.f;
                if (mx > -INFINITY) {
#pragma unroll
                    for (int n = 0; n < 4; ++n)
                        if (v[n] > -INFINITY) s += __expf(v[n] - mx);
                }
#pragma unroll
                for (int off = 1; off < 16; off <<= 1) s += __shfl_xor(s, off);
                if (ln == 0) {
                    int row = wr * 64 + m * 16 + hi * 4 + j;
                    redm[row][wc] = mx;
                    reds[row][wc] = s;
                }
            }
        }
        __syncthreads();
        if (tid < 128) {
            float m0 = redm[tid][0], m1 = redm[tid][1];
            float s0 = reds[tid][0], s1 = reds[tid][1];
            float M = fmaxf(m0, m1);
            float S = 0.f;
            if (m0 > -INFINITY) S += s0 * __expf(m0 - M);
            if (m1 > -INFINITY) S += s1 * __expf(m1 - M);
            float2* pp = (float2*)o1;
            pp[((size_t)z * 9 + bn) * NPAD_ + bm * 128 + tid] = make_float2(M, S);
        }
    }
}

// =================== v (B,H,1152,96) -> vT (B,H,96,1152) ===================
__global__ __launch_bounds__(256) void transpose_v(const u16* __restrict__ vb,
                                                   u16* __restrict__ vtb) {
    __shared__ u16 t[32][34];
    int bi = blockIdx.x, bj = blockIdx.y, z = blockIdx.z;
    const u16* ib = vb + (size_t)z * NPAD_ * HD_;
    u16* ob = vtb + (size_t)z * HD_ * NPAD_;
    int tid = threadIdx.x;
    int r = tid >> 3, c = (tid & 7) * 4;
    *(u16x4*)&t[r][c] = *(const u16x4*)(ib + (size_t)(bi * 32 + r) * HD_ + bj * 32 + c);
    __syncthreads();
    u16x4 o;
    o[0] = t[c + 0][r]; o[1] = t[c + 1][r]; o[2] = t[c + 2][r]; o[3] = t[c + 3][r];
    *(u16x4*)(ob + (size_t)(bj * 32 + r) * NPAD_ + bi * 32 + c) = o;
}

// =================== fused softmax + PV ===================
// grid (33, 64): 32-row tile of one (b,h). Reads raw once, writes attn,
// keeps P bf16 in LDS, MFMA with vT -> acat bf16.
__global__ __launch_bounds__(256) void attn_pv(const float* __restrict__ raw,
                                               float* __restrict__ attn,
                                               const float2* __restrict__ part,
                                               const u16* __restrict__ vtb,
                                               u16* __restrict__ acat) {
    __shared__ u16 Ps[32][1064];
    __shared__ u16 Bs[96][40];
    __shared__ float sm[32], si[32];
    const int tid = threadIdx.x;
    const int bi = blockIdx.x, z = blockIdx.y;
    // combine the 9 j-tile partials per row
    if (tid < 32) {
        int grow = bi * 32 + tid;
        float M = -INFINITY;
        float mj[9], sj[9];
#pragma unroll
        for (int jt = 0; jt < 9; ++jt) {
            float2 p = part[((size_t)z * 9 + jt) * NPAD_ + grow];
            mj[jt] = p.x; sj[jt] = p.y;
            M = fmaxf(M, p.x);
        }
        float S = 0.f;
#pragma unroll
        for (int jt = 0; jt < 9; ++jt)
            if (mj[jt] > -INFINITY) S += sj[jt] * __expf(mj[jt] - M);
        sm[tid] = M;
        si[tid] = 1.f / S;
    }
    __syncthreads();
    // phase 2: read raw, write attn, fill P (bf16) in LDS
    {
        int r = tid >> 3, l8 = tid & 7;
        int grow = bi * 32 + r;
        bool vrow = grow < NTOK_;
        float m_r = sm[r], inv_r = si[r];
        const float* rp = raw + (size_t)z * NTOK_ * NTOK_ + (size_t)(vrow ? grow : 0) * NTOK_;
        float* apw = attn + (size_t)z * NTOK_ * NTOK_ + (size_t)(vrow ? grow : 0) * NTOK_;
#pragma unroll 4
        for (int j = 0; j < 33; ++j) {
            int col = l8 * 4 + j * 32;
            bool ok = vrow && (col < NTOK_);
            u16x4 pb = {0, 0, 0, 0};
            if (ok) {
                float4 v = *(const float4*)(rp + col);
                float4 p;
                p.x = __expf(v.x * SCALE_SPA - m_r) * inv_r;
                p.y = __expf(v.y * SCALE_SPA - m_r) * inv_r;
                p.z = __expf(v.z * SCALE_SPA - m_r) * inv_r;
                p.w = __expf(v.w * SCALE_SPA - m_r) * inv_r;
                *(float4*)(apw + col) = p;
                pb[0] = f2b_fast(p.x); pb[1] = f2b_fast(p.y);
                pb[2] = f2b_fast(p.z); pb[3] = f2b_fast(p.w);
            }
            *(u16x4*)&Ps[r][col] = pb;
        }
    }
    // phase 3: PV MFMA (M=32, N=96, K=1056)
    const int lane = tid & 63, wid = tid >> 6;
    const int ln = lane & 15, hi = lane >> 4;
    const int wr = wid >> 1, wc = wid & 1;
    const u16* vp = vtb + (size_t)z * HD_ * NPAD_;
    f32x4 acc[3] = {};
    for (int kt = 0; kt < 1056; kt += 32) {
        __syncthreads();
        if (tid < 192) {
            int row = tid >> 1, half = tid & 1;
            const u16* gb = vp + (size_t)row * NPAD_ + kt + half * 16;
            *(u16x8*)&Bs[row][half * 16] = *(const u16x8*)gb;
            *(u16x8*)&Bs[row][half * 16 + 8] = *(const u16x8*)(gb + 8);
        }
        __syncthreads();
        bf16x8 af = *(const bf16x8*)&Ps[wr * 16 + ln][kt + hi * 8];
        bf16x8 bfr[3];
#pragma unroll
        for (int n = 0; n < 3; ++n) bfr[n] = *(const bf16x8*)&Bs[wc * 48 + n * 16 + ln][hi * 8];
#pragma unroll
        for (int n = 0; n < 3; ++n)
            acc[n] = __builtin_amdgcn_mfma_f32_16x16x32_bf16(af, bfr[n], acc[n], 0, 0, 0);
    }
    int b = z >> 3, h = z & 7;
#pragma unroll
    for (int n = 0; n < 3; ++n)
#pragma unroll
        for (int j = 0; j < 4; ++j) {
            int gi = bi * 32 + wr * 16 + hi * 4 + j;
            if (gi < NTOK_) {
                int gd = wc * 48 + n * 16 + ln;
                acat[((size_t)b * NTOK_ + gi) * DIM_ + h * HD_ + gd] = f2b(acc[n][j]);
            }
        }
}

// =================== windowed channel scores (bf16 chanp) ===================
__global__ __launch_bounds__(256) void chan_scores(const u16* __restrict__ chanpb,
                                                   const float* __restrict__ x,
                                                   float* __restrict__ rawchan_ws,
                                                   float* __restrict__ out_raw) {
    int blk = blockIdx.x;  // b*16 + w
    int b = blk / 16, w = blk % 16;
    int cy = blockIdx.y;   // 6 chunks of 8 cc
    int nh = w / 4, nw = w % 4;
    __shared__ float qp[16][65];
    __shared__ float xs[64][17];
    int tid = threadIdx.x;
    for (int l = tid; l < 16 * 64; l += 256) {
        int t = l / 64, d = l % 64;
        int wh = d / 8, ww = d % 8;
        int pix = (nh * 8 + wh) * 32 + nw * 8 + ww;
        qp[t][d] = b2f(chanpb[((size_t)b * NT_ + t) * PIX_ + pix]);
    }
    __syncthreads();
    int t = tid % 16, cl = tid / 16;
    for (int cc = cy * 8; cc < cy * 8 + 8; ++cc) {
        for (int l = tid; l < 64 * 16; l += 256) {
            int d = l / 16, c2 = l % 16;
            int wh = d / 8, ww = d % 8;
            int pix = (nh * 8 + wh) * 32 + nw * 8 + ww;
            xs[d][c2] = x[((size_t)b * PIX_ + pix) * DIM_ + cc * 16 + c2];
        }
        __syncthreads();
        float acc = 0.f;
#pragma unroll
        for (int d = 0; d < 64; ++d) acc += qp[t][d] * xs[d][cl];
        int c = cc * 16 + cl;
        rawchan_ws[(((size_t)b * 16 + w) * NT_ + t) * DIM_ + c] = acc;
        out_raw[(((size_t)b * NT_ + t) * DIM_ + c) * 16 + w] = acc;
        __syncthreads();
    }
}

// =================== chan softmax over c (768), scattered write ===================
__global__ __launch_bounds__(256) void chan_softmax(const float* __restrict__ rawchan_ws,
                                                    float* __restrict__ out_attn) {
    int row = blockIdx.x;  // (b*16+w)*16 + t
    int b = row / 256;
    int w = (row / 16) % 16;
    int t = row % 16;
    const float* rp = rawchan_ws + (size_t)row * DIM_;
    int tid = threadIdx.x;
    float vals[3];
    float m = -INFINITY;
#pragma unroll
    for (int i = 0; i < 3; ++i) {
        vals[i] = rp[tid + i * 256] * 0.125f;
        m = fmaxf(m, vals[i]);
    }
    __shared__ float redm[4], reds[4];
    for (int off = 32; off; off >>= 1) m = fmaxf(m, __shfl_xor(m, off));
    if ((tid & 63) == 0) redm[tid >> 6] = m;
    __syncthreads();
    m = fmaxf(fmaxf(redm[0], redm[1]), fmaxf(redm[2], redm[3]));
    float s = 0.f;
#pragma unroll
    for (int i = 0; i < 3; ++i) { vals[i] = __expf(vals[i] - m); s += vals[i]; }
    for (int off = 32; off; off >>= 1) s += __shfl_xor(s, off);
    if ((tid & 63) == 0) reds[tid >> 6] = s;
    __syncthreads();
    s = reds[0] + reds[1] + reds[2] + reds[3];
    float inv = 1.f / s;
#pragma unroll
    for (int i = 0; i < 3; ++i) {
        int c = tid + i * 256;
        out_attn[(((size_t)b * NT_ + t) * DIM_ + c) * 16 + w] = vals[i] * inv;
    }
}

// =================== quaternion double conv (per (b,t) block) ===================
__global__ __launch_bounds__(256) void quat_conv(const float* __restrict__ tp,
                                                 const float* __restrict__ tpo,
                                                 const float* __restrict__ chp,
                                                 const float* __restrict__ qf_r, const float* __restrict__ qf_i,
                                                 const float* __restrict__ qf_j, const float* __restrict__ qf_k,
                                                 const float* __restrict__ qf_b,
                                                 const float* __restrict__ dqf_r, const float* __restrict__ dqf_i,
                                                 const float* __restrict__ dqf_j, const float* __restrict__ dqf_k,
                                                 const float* __restrict__ dqf_b,
                                                 float* __restrict__ fe2_out,
                                                 float* __restrict__ partials) {
    int blk = blockIdx.x;  // b*16 + t
    int b = blk / NT_, t = blk % NT_;
    __shared__ float w1[8][4][3];
    __shared__ float w2[8][4][3];
    __shared__ float w2c[4][8][3];
    __shared__ float qs[4][770];
    __shared__ float fs[8][770];
    __shared__ float wsum[4][4], wsq[4][4];
    int tid = threadIdx.x;
    if (tid < 96) {
        int o = tid / 12, rest = tid % 12, ic = rest / 3, tap = rest % 3;
        int g = o / 2, oo = o % 2;
        const int   cidx[4][4] = {{0, 1, 2, 3}, {1, 0, 3, 2}, {2, 3, 0, 1}, {3, 2, 1, 0}};
        const float csgn[4][4] = {{1, -1, -1, -1}, {1, 1, -1, 1}, {1, 1, 1, -1}, {1, -1, 1, 1}};
        const float* s1[4] = {qf_r, qf_i, qf_j, qf_k};
        const float* s2[4] = {dqf_r, dqf_i, dqf_j, dqf_k};
        w1[o][ic][tap] = csgn[g][ic] * s1[cidx[g][ic]][oo * 3 + tap];
        w2[o][ic][tap] = csgn[g][ic] * s2[cidx[g][ic]][oo * 3 + tap];
    }
    for (int l = tid; l < DIM_; l += 256) {
        size_t base = ((size_t)b * NT_ + t) * DIM_ + l;
        qs[0][1 + l] = 0.f;
        qs[1][1 + l] = tp[base];
        qs[2][1 + l] = tpo[base];
        qs[3][1 + l] = chp[base];
    }
    if (tid < 4) { qs[tid][0] = 0.f; qs[tid][769] = 0.f; }
    if (tid < 8) { fs[tid][0] = 0.f; fs[tid][769] = 0.f; }
    __syncthreads();
    if (tid < 96) {
        int o2 = tid / 24, rest = tid % 24, i2 = rest / 3, tap = rest % 3;
        w2c[o2][i2][tap] = w2[i2][o2][2 - tap];
    }
    for (int l = tid; l < DIM_; l += 256) {
#pragma unroll
        for (int o = 0; o < 8; ++o) {
            float a = qf_b[o];
#pragma unroll
            for (int ic = 0; ic < 4; ++ic)
#pragma unroll
                for (int tap = 0; tap < 3; ++tap) a += w1[o][ic][tap] * qs[ic][l + tap];
            fs[o][1 + l] = a;
        }
    }
    __syncthreads();
    float lsum[4] = {}, lsq[4] = {};
    for (int l = tid; l < DIM_; l += 256) {
#pragma unroll
        for (int o2 = 0; o2 < 4; ++o2) {
            float a = dqf_b[o2];
#pragma unroll
            for (int i2 = 0; i2 < 8; ++i2)
#pragma unroll
                for (int tap = 0; tap < 3; ++tap) a += w2c[o2][i2][tap] * fs[i2][l + tap];
            fe2_out[((size_t)blk * 4 + o2) * DIM_ + l] = a;
            lsum[o2] += a;
            lsq[o2] += a * a;
        }
    }
    int wid = tid >> 6;
#pragma unroll
    for (int o2 = 0; o2 < 4; ++o2) {
        float s = lsum[o2], q = lsq[o2];
        for (int off = 32; off; off >>= 1) { s += __shfl_xor(s, off); q += __shfl_xor(q, off); }
        if ((tid & 63) == 0) { wsum[wid][o2] = s; wsq[wid][o2] = q; }
    }
    __syncthreads();
    if (tid < 4) {
        float s = wsum[0][tid] + wsum[1][tid] + wsum[2][tid] + wsum[3][tid];
        float q = wsq[0][tid] + wsq[1][tid] + wsq[2][tid] + wsq[3][tid];
        partials[(size_t)blk * 8 + tid * 2 + 0] = s;
        partials[(size_t)blk * 8 + tid * 2 + 1] = q;
    }
}

// =================== BN + exact GELU + channel mix ===================
__global__ __launch_bounds__(256) void bn_gelu_out(const float* __restrict__ fe2,
                                                   const float* __restrict__ partials,
                                                   const float* __restrict__ bn_g,
                                                   const float* __restrict__ bn_b,
                                                   const float* __restrict__ qfto,
                                                   float* __restrict__ out5) {
    int blk = blockIdx.x;  // b*16 + t
    int b = blk / NT_;
    int tid = threadIdx.x;
    float mean[4], rstd[4], gam[4], bet[4], qw[4];
#pragma unroll
    for (int kk = 0; kk < 4; ++kk) {
        float s = 0.f, q = 0.f;
        for (int t2 = 0; t2 < 16; ++t2) {
            const float* p = partials + ((size_t)(b * NT_ + t2) * 8 + kk * 2);
            s += p[0];
            q += p[1];
        }
        float mu = s * (1.f / 12288.f);
        float var = q * (1.f / 12288.f) - mu * mu;
        mean[kk] = mu;
        rstd[kk] = rsqrtf(var + 1e-5f);
        gam[kk] = bn_g[kk];
        bet[kk] = bn_b[kk];
        qw[kk] = qfto[kk];
    }
    for (int l = tid; l < DIM_; l += 256) {
        float acc = 0.f;
#pragma unroll
        for (int kk = 0; kk < 4; ++kk) {
            float v = fe2[((size_t)blk * 4 + kk) * DIM_ + l];
            float nrm = (v - mean[kk]) * rstd[kk] * gam[kk] + bet[kk];
            float ge = 0.5f * nrm * (1.f + erff(nrm * 0.7071067811865475f));
            acc += ge * qw[kk];
        }
        out5[(size_t)blk * DIM_ + l] = acc;
    }
}

// =================== launch ===================
extern "C" void kernel_launch(void* const* d_in, const int* in_sizes, int n_in,
                              void* d_out, int out_size, void* d_ws, size_t ws_size,
                              hipStream_t stream) {
    const float* x      = (const float*)d_in[0];
    const float* tp     = (const float*)d_in[1];
    const float* qkv_w  = (const float*)d_in[2];
    const float* proj_w = (const float*)d_in[3];
    const float* proj_b = (const float*)d_in[4];
    const float* tt_w   = (const float*)d_in[5];
    const float* tt_b   = (const float*)d_in[6];
    const float* tt1_w  = (const float*)d_in[7];
    const float* tt1_b  = (const float*)d_in[8];
    const float* qf_r   = (const float*)d_in[9];
    const float* qf_i   = (const float*)d_in[10];
    const float* qf_j   = (const float*)d_in[11];
    const float* qf_k   = (const float*)d_in[12];
    const float* qf_b   = (const float*)d_in[13];
    const float* dqf_r  = (const float*)d_in[14];
    const float* dqf_i  = (const float*)d_in[15];
    const float* dqf_j  = (const float*)d_in[16];
    const float* dqf_k  = (const float*)d_in[17];
    const float* dqf_b  = (const float*)d_in[18];
    const float* bn_g   = (const float*)d_in[19];
    const float* bn_b   = (const float*)d_in[20];
    const float* qfto   = (const float*)d_in[21];
    float* out = (float*)d_out;
    char* wsb = (char*)d_ws;

    u16* xcb    = (u16*)(wsb + WSO_XCB);
    u16* wqkvb  = (u16*)(wsb + WSO_WQKV);
    u16* wprojb = (u16*)(wsb + WSO_WPROJ);
    u16* qb     = (u16*)(wsb + WSO_QB);
    u16* kb     = (u16*)(wsb + WSO_KB);
    u16* vb     = (u16*)(wsb + WSO_VB);
    u16* vtb    = (u16*)(wsb + WSO_VTB);
    u16* acatb  = (u16*)(wsb + WSO_ACATB);
    u16* tpb    = (u16*)(wsb + WSO_TPB);
    u16* ttwb   = (u16*)(wsb + WSO_TTWB);
    u16* tt1wb  = (u16*)(wsb + WSO_TT1WB);
    u16* chanpb = (u16*)(wsb + WSO_CHANPB);
    float* partb = (float*)(wsb + WSO_PART);
    float* f32r = (float*)(wsb + WSO_F32);
    float* tpout   = f32r + FO_TPOUT;
    float* rawchan = f32r + FO_RAWCHAN;
    float* chpf    = f32r + FO_CHP;
    float* fe2     = f32r + FO_FE2;
    float* stats   = f32r + FO_STATS;

    // casts
    cast_concat<<<3120, 256, 0, stream>>>(tp, x, xcb);
    cast8<<<864, 256, 0, stream>>>(qkv_w, wqkvb, 221184);
    cast8<<<288, 256, 0, stream>>>(proj_w, wprojb, 73728);
    cast8<<<48, 256, 0, stream>>>(tp, tpb, 12288);
    cast8<<<384, 256, 0, stream>>>(tt_w, ttwb, 98304);
    cast8<<<384, 256, 0, stream>>>(tt1_w, tt1wb, 98304);

    // QKV: (8320x768) @ (2304x768)^T -> q,k,v bf16 row-major
    gemm_bf16<0><<<dim3(65, 18, 1), 256, 0, stream>>>(xcb, wqkvb, 768, 768, 768, 0, 0,
                                                      nullptr, nullptr, nullptr, qb, kb, vb, 0);
    // v -> vT
    transpose_v<<<dim3(36, 3, 64), 256, 0, stream>>>(vb, vtb);
    // scores -> raw (output 2) + softmax partials
    gemm_bf16<1><<<dim3(9, 9, 64), 256, 0, stream>>>(qb, kb, 96, 96, 96,
                                                     (size_t)NPAD_ * HD_, (size_t)NPAD_ * HD_,
                                                     nullptr, out + OUT_RAW, partb,
                                                     nullptr, nullptr, nullptr, 0);
    // fused softmax (output 3) + PV -> acat bf16
    attn_pv<<<dim3(33, 64), 256, 0, stream>>>(out + OUT_RAW, out + OUT_ATTN,
                                              (const float2*)partb, vtb, acatb);
    // proj -> x_out (output 1) + tp_out
    gemm_bf16<2><<<dim3(65, 6, 1), 256, 0, stream>>>(acatb, wprojb, 768, 768, 768, 0, 0,
                                                     proj_b, out + OUT_XOUT, tpout,
                                                     nullptr, nullptr, nullptr, 0);
    // chanp = tp @ tt_w^T + tt_b  (bf16 out)
    gemm_bf16<3><<<dim3(1, 8, 1), 256, 0, stream>>>(tpb, ttwb, 768, 768, 768, 0, 0,
                                                    tt_b, nullptr, nullptr, chanpb, nullptr, nullptr, 1024);
    // windowed channel scores (output 4 + ws)
    chan_scores<<<dim3(128, 6), 256, 0, stream>>>(chanpb, x, rawchan, out + OUT_RAWCH);
    // chan softmax (output 5)
    chan_softmax<<<2048, 256, 0, stream>>>(rawchan, out + OUT_ATTNCH);
    // ch_prompts = chanp @ tt1_w^T + tt1_b  (fp32 out)
    gemm_bf16<4><<<dim3(1, 6, 1), 256, 0, stream>>>(chanpb, tt1wb, 1024, 1024, 1024, 0, 0,
                                                    tt1_b, chpf, nullptr, nullptr, nullptr, nullptr, 768);
    // quaternion conv + BN + GELU + mix (output 6)
    quat_conv<<<128, 256, 0, stream>>>(tp, tpout, chpf,
                                       qf_r, qf_i, qf_j, qf_k, qf_b,
                                       dqf_r, dqf_i, dqf_j, dqf_k, dqf_b,
                                       fe2, stats);
    bn_gelu_out<<<128, 256, 0, stream>>>(fe2, stats, bn_g, bn_b, qfto, out + OUT_QOUT);
}